// Round 2
// baseline (1910.493 us; speedup 1.0000x reference)
//
#include <hip/hip_runtime.h>
#include <hip/hip_bf16.h>

static constexpr float EPS_ = 1e-5f;
static constexpr float NEG_ = 0.01f;

using u16 = unsigned short;

static __device__ __forceinline__ float bf2f(u16 u) {
    return __uint_as_float(((unsigned)u) << 16);
}
static __device__ __forceinline__ u16 f2bf(float f) {
    union { __hip_bfloat16 h; u16 u; } c;
    c.h = __float2bfloat16(f);
    return c.u;
}

// ---------------------------------------------------------------------------
// Generic tiled GEMM: C[m][j] = sum_k A[m][k]*W[k][j] + bias[j] (+epilogue)
// Tile 64x64, K-chunk 16, 256 threads, 4x4 per thread.
// AMODE: 0 = A row m direct; 1 = A in (n,h,q,e) layout, m = n*2048+q*16+h (local)
// SMODE: 0 = out[m*Nn+j]; 1 = store to (n,h,l,e) layout (local n)
// EPI:   0 = plain; 1 = leaky; 2 = + res[m*Nn+j]
// AN:    apply per-row affine (anp[m&2047]) to A elements (fused batchnorm)
// RN:    apply per-row affine (rnp[m&2047]) to res elements (fused batchnorm)
// TA/TR: float or u16(bf16); TO: float or u16(bf16)
// ---------------------------------------------------------------------------
template<int AMODE, int SMODE, int EPI, int AN, int RN,
         typename TA, typename TR, typename TO>
__global__ __launch_bounds__(256) void gemm_k(
    const TA* __restrict__ A, const float* __restrict__ W,
    const float* __restrict__ bias, const TR* __restrict__ res,
    const float2* __restrict__ anp, const float2* __restrict__ rnp,
    TO* __restrict__ out, int K, int Nn)
{
    __shared__ float As[16][65];
    __shared__ float Ws[16][64];
    const int tid = threadIdx.x;
    const int tx = tid & 15, ty = tid >> 4;
    const int m0 = blockIdx.y * 64, n0 = blockIdx.x * 64;
    const int lr = tid >> 2;          // 0..63: A row within tile
    const int lk = (tid & 3) * 4;     // k offset within chunk

    const int mload = m0 + lr;
    const TA* arow;
    if constexpr (AMODE == 0) {
        arow = A + (size_t)mload * K;
    } else {
        const int n = mload >> 11, qh = mload & 2047, q = qh >> 4, h = qh & 15;
        arow = A + ((size_t)(n * 16 + h) * 128 + q) * K;
    }
    float apa = 1.f, apb = 0.f;
    if constexpr (AN) { const float2 p = anp[mload & 2047]; apa = p.x; apb = p.y; }

    const int kr = tid >> 4;          // 0..15: W row within chunk
    const int wc = (tid & 15) * 4;    // W col within tile

    float acc[4][4] = {};

    for (int k0 = 0; k0 < K; k0 += 16) {
        float a4[4];
        if constexpr (sizeof(TA) == 4) {
            const float4 t = *(const float4*)((const float*)arow + k0 + lk);
            a4[0] = t.x; a4[1] = t.y; a4[2] = t.z; a4[3] = t.w;
        } else {
            const ushort4 t = *(const ushort4*)((const u16*)arow + k0 + lk);
            a4[0] = bf2f(t.x); a4[1] = bf2f(t.y);
            a4[2] = bf2f(t.z); a4[3] = bf2f(t.w);
        }
        if constexpr (AN) {
            #pragma unroll
            for (int i = 0; i < 4; i++) a4[i] = a4[i] * apa + apb;
        }
        #pragma unroll
        for (int i = 0; i < 4; i++) As[lk + i][lr] = a4[i];
        const float4 w4 = *(const float4*)(W + (size_t)(k0 + kr) * Nn + n0 + wc);
        Ws[kr][wc + 0] = w4.x; Ws[kr][wc + 1] = w4.y;
        Ws[kr][wc + 2] = w4.z; Ws[kr][wc + 3] = w4.w;
        __syncthreads();
        #pragma unroll
        for (int kk = 0; kk < 16; kk++) {
            float a[4], b[4];
            #pragma unroll
            for (int i = 0; i < 4; i++) a[i] = As[kk][ty * 4 + i];
            #pragma unroll
            for (int j = 0; j < 4; j++) b[j] = Ws[kk][tx * 4 + j];
            #pragma unroll
            for (int i = 0; i < 4; i++)
                #pragma unroll
                for (int j = 0; j < 4; j++) acc[i][j] += a[i] * b[j];
        }
        __syncthreads();
    }

    #pragma unroll
    for (int i = 0; i < 4; i++) {
        const int m = m0 + ty * 4 + i;
        float rpa = 1.f, rpb = 0.f;
        if constexpr (EPI == 2 && RN) {
            const float2 p = rnp[m & 2047]; rpa = p.x; rpb = p.y;
        }
        #pragma unroll
        for (int j = 0; j < 4; j++) {
            const int jj = n0 + tx * 4 + j;
            float vv = acc[i][j] + bias[jj];
            if constexpr (EPI == 2) {
                float rv;
                if constexpr (sizeof(TR) == 4)
                    rv = ((const float*)res)[(size_t)m * Nn + jj];
                else
                    rv = bf2f(((const u16*)res)[(size_t)m * Nn + jj]);
                if constexpr (RN) rv = rv * rpa + rpb;
                vv += rv;
            }
            if constexpr (EPI == 1) vv = vv >= 0.f ? vv : NEG_ * vv;
            size_t oidx;
            if constexpr (SMODE == 0) {
                oidx = (size_t)m * Nn + jj;
            } else {
                const int n = m >> 11, lh = m & 2047, l = lh >> 4, h = lh & 15;
                oidx = ((size_t)(n * 16 + h) * 128 + l) * Nn + jj;
            }
            if constexpr (sizeof(TO) == 2) out[oidx] = f2bf(vv);
            else                           out[oidx] = vv;
        }
    }
}

// ---------------------------------------------------------------------------
// Batched [qk*(1/16) | QE], chunk-local: b in [0,128), h = b&15 (global h)
//   j<128 : sum_e q[b][i][e]*k[b][j][e] / 16
//   j>=128: sum_e q[b][i][e]*Erel[h][j-128][e]
// grid (4, 2, 128); q,k bf16; erel f32
// ---------------------------------------------------------------------------
__global__ __launch_bounds__(256) void qkqe_k(
    const u16* __restrict__ q, const u16* __restrict__ kp,
    const float* __restrict__ erel, float* __restrict__ out)
{
    const int b = blockIdx.z, h = b & 15;
    const int m0 = blockIdx.y * 64, n0 = blockIdx.x * 64;
    __shared__ float Qs[16][65];
    __shared__ float Bs[16][65];
    const int tid = threadIdx.x;
    const int tx = tid & 15, ty = tid >> 4;
    const int lr = tid >> 2, lk = (tid & 3) * 4;

    const u16* qrow = q + ((size_t)b * 128 + m0 + lr) * 256;
    const int jj = n0 + lr;
    const u16* krow = kp + ((size_t)b * 128 + jj) * 256;            // valid jj<128
    const float* erow = erel + ((size_t)h * 128 + (jj - 128)) * 256; // valid jj>=128

    float acc[4][4] = {};
    for (int k0 = 0; k0 < 256; k0 += 16) {
        const ushort4 qt = *(const ushort4*)(qrow + k0 + lk);
        Qs[lk + 0][lr] = bf2f(qt.x); Qs[lk + 1][lr] = bf2f(qt.y);
        Qs[lk + 2][lr] = bf2f(qt.z); Qs[lk + 3][lr] = bf2f(qt.w);
        float b0, b1, b2, b3;
        if (jj < 128) {
            const ushort4 kt = *(const ushort4*)(krow + k0 + lk);
            b0 = bf2f(kt.x); b1 = bf2f(kt.y); b2 = bf2f(kt.z); b3 = bf2f(kt.w);
        } else {
            const float4 et = *(const float4*)(erow + k0 + lk);
            b0 = et.x; b1 = et.y; b2 = et.z; b3 = et.w;
        }
        Bs[lk + 0][lr] = b0; Bs[lk + 1][lr] = b1;
        Bs[lk + 2][lr] = b2; Bs[lk + 3][lr] = b3;
        __syncthreads();
        #pragma unroll
        for (int kk = 0; kk < 16; kk++) {
            float a[4], bb[4];
            #pragma unroll
            for (int i = 0; i < 4; i++) a[i] = Qs[kk][ty * 4 + i];
            #pragma unroll
            for (int j = 0; j < 4; j++) bb[j] = Bs[kk][tx * 4 + j];
            #pragma unroll
            for (int i = 0; i < 4; i++)
                #pragma unroll
                for (int j = 0; j < 4; j++) acc[i][j] += a[i] * bb[j];
        }
        __syncthreads();
    }
    const float scale = (n0 < 128) ? 0.0625f : 1.0f;
    #pragma unroll
    for (int i = 0; i < 4; i++)
        #pragma unroll
        for (int j = 0; j < 4; j++)
            out[((size_t)b * 128 + m0 + ty * 4 + i) * 256 + n0 + tx * 4 + j] =
                acc[i][j] * scale;
}

// ---------------------------------------------------------------------------
// softmax over qk row + skewed-S add (chunk-local rows)
// one wave per row, 4 waves/block
// S[i,c] = QE[i, 127-i+c] for c<=i else 0  (QE at row offset 128)
// ---------------------------------------------------------------------------
__global__ __launch_bounds__(256) void softmax_k(
    const float* __restrict__ qkqe, float* __restrict__ att)
{
    const int r = blockIdx.x * 4 + (threadIdx.x >> 6);
    const int lane = threadIdx.x & 63;
    const int i = r & 127;
    const float* row = qkqe + (size_t)r * 256;
    const float x0 = row[lane], x1 = row[lane + 64];
    float mx = fmaxf(x0, x1);
    #pragma unroll
    for (int o = 32; o; o >>= 1) mx = fmaxf(mx, __shfl_xor(mx, o));
    const float e0 = __expf(x0 - mx), e1 = __expf(x1 - mx);
    float s = e0 + e1;
    #pragma unroll
    for (int o = 32; o; o >>= 1) s += __shfl_xor(s, o);
    const float rinv = 1.0f / s;
    const int j0 = lane, j1 = lane + 64;
    const float s0 = (j0 <= i) ? row[128 + 127 - i + j0] : 0.f;
    const float s1 = (j1 <= i) ? row[128 + 127 - i + j1] : 0.f;
    att[(size_t)r * 128 + j0] = e0 * rinv + s0;
    att[(size_t)r * 128 + j1] = e1 * rinv + s1;
}

// ---------------------------------------------------------------------------
// z[b] = att[b] (128x128 f32) @ v[b] (128x256 bf16) -> bf16, grid (4,2,128)
// ---------------------------------------------------------------------------
__global__ __launch_bounds__(256) void av_k(
    const float* __restrict__ att, const u16* __restrict__ v,
    u16* __restrict__ z)
{
    const int b = blockIdx.z;
    const int m0 = blockIdx.y * 64, n0 = blockIdx.x * 64;
    __shared__ float As[16][65];
    __shared__ float Vs[16][64];
    const int tid = threadIdx.x;
    const int tx = tid & 15, ty = tid >> 4;
    const int lr = tid >> 2, lk = (tid & 3) * 4;
    const float* ab = att + (size_t)b * 128 * 128;
    const u16* vb = v + (size_t)b * 128 * 256;
    const int kr = tid >> 4, wc = (tid & 15) * 4;

    float acc[4][4] = {};
    for (int k0 = 0; k0 < 128; k0 += 16) {
        const float4 a4 = *(const float4*)(ab + (size_t)(m0 + lr) * 128 + k0 + lk);
        As[lk + 0][lr] = a4.x; As[lk + 1][lr] = a4.y;
        As[lk + 2][lr] = a4.z; As[lk + 3][lr] = a4.w;
        const ushort4 w4 = *(const ushort4*)(vb + (size_t)(k0 + kr) * 256 + n0 + wc);
        Vs[kr][wc + 0] = bf2f(w4.x); Vs[kr][wc + 1] = bf2f(w4.y);
        Vs[kr][wc + 2] = bf2f(w4.z); Vs[kr][wc + 3] = bf2f(w4.w);
        __syncthreads();
        #pragma unroll
        for (int kk = 0; kk < 16; kk++) {
            float a[4], bb[4];
            #pragma unroll
            for (int i = 0; i < 4; i++) a[i] = As[kk][ty * 4 + i];
            #pragma unroll
            for (int j = 0; j < 4; j++) bb[j] = Vs[kk][tx * 4 + j];
            #pragma unroll
            for (int i = 0; i < 4; i++)
                #pragma unroll
                for (int j = 0; j < 4; j++) acc[i][j] += a[i] * bb[j];
        }
        __syncthreads();
    }
    #pragma unroll
    for (int i = 0; i < 4; i++)
        #pragma unroll
        for (int j = 0; j < 4; j++)
            z[((size_t)b * 128 + m0 + ty * 4 + i) * 256 + n0 + tx * 4 + j] =
                f2bf(acc[i][j]);
}

// ---------------------------------------------------------------------------
// batchnorm stats over axes (n, e) per channel c (input bf16, full 65536 rows)
// params[c] = (a, b): h = x*a + b with a = g*rsqrt(var+eps), b = be - mean*a
// ---------------------------------------------------------------------------
__global__ __launch_bounds__(256) void bnstats_k(
    const u16* __restrict__ x, const float* __restrict__ g,
    const float* __restrict__ be, float2* __restrict__ params)
{
    const int c = blockIdx.x, tid = threadIdx.x;
    float s = 0.f, s2 = 0.f;
    #pragma unroll 4
    for (int n = 0; n < 32; n++) {
        const float v = bf2f(x[((size_t)n * 2048 + c) * 256 + tid]);
        s += v; s2 += v * v;
    }
    #pragma unroll
    for (int o = 32; o; o >>= 1) { s += __shfl_xor(s, o); s2 += __shfl_xor(s2, o); }
    __shared__ float rs[4], rs2[4];
    const int w = tid >> 6;
    if ((tid & 63) == 0) { rs[w] = s; rs2[w] = s2; }
    __syncthreads();
    if (tid == 0) {
        s  = rs[0] + rs[1] + rs[2] + rs[3];
        s2 = rs2[0] + rs2[1] + rs2[2] + rs2[3];
        const float mean = s / 8192.f;
        const float var = s2 / 8192.f - mean * mean;
        const float a = g[c] * rsqrtf(var + EPS_);
        params[c] = make_float2(a, be[c] - mean * a);
    }
}

// ---------------------------------------------------------------------------
extern "C" void kernel_launch(void* const* d_in, const int* in_sizes, int n_in,
                              void* d_out, int out_size, void* d_ws, size_t ws_size,
                              hipStream_t stream)
{
    const float* x    = (const float*)d_in[0];
    const float* Wq   = (const float*)d_in[1];
    const float* bq   = (const float*)d_in[2];
    const float* Wk   = (const float*)d_in[3];
    const float* bk   = (const float*)d_in[4];
    const float* Wv   = (const float*)d_in[5];
    const float* bv   = (const float*)d_in[6];
    const float* Erel = (const float*)d_in[7];
    const float* Wo   = (const float*)d_in[8];
    const float* bo   = (const float*)d_in[9];
    const float* g1   = (const float*)d_in[10];
    const float* be1  = (const float*)d_in[11];
    const float* g2   = (const float*)d_in[12];
    const float* be2  = (const float*)d_in[13];
    const float* W1   = (const float*)d_in[14];
    const float* b1   = (const float*)d_in[15];
    const float* W2   = (const float*)d_in[16];
    const float* b2   = (const float*)d_in[17];
    const float* Wenc = (const float*)d_in[18];
    const float* benc = (const float*)d_in[19];

    char* ws = (char*)d_ws;
    const size_t MB = 1ull << 20;
    // attention chunk scratch (reused 4x), ~56 MB
    u16*   qc   = (u16*)(ws + 0 * MB);     // 8 MB  (128,128,256) bf16
    u16*   kc   = (u16*)(ws + 8 * MB);     // 8 MB
    u16*   vc   = (u16*)(ws + 16 * MB);    // 8 MB
    float* qkc  = (float*)(ws + 24 * MB);  // 16 MB (128,128,256) f32
    float* attc = (float*)(ws + 40 * MB);  // 8 MB  (128,128,128) f32
    u16*   zc   = (u16*)(ws + 48 * MB);    // 8 MB  bf16
    // persistent
    u16*   h1pre = (u16*)(ws + 56 * MB);   // 32 MB (65536,256) bf16
    u16*   h2pre = (u16*)(ws + 88 * MB);   // 32 MB bf16
    // FFN chunk scratch (reuses attention scratch region)
    u16*   ff1  = (u16*)(ws + 0 * MB);     // 32 MB (16384,1024) bf16
    float2* p1  = (float2*)(ws + 120 * MB);
    float2* p2  = (float2*)(ws + 120 * MB + 64 * 1024);

    const dim3 blk(256);

    // ---- Phase 1: attention, chunked over n (4 chunks x 8 n) ----
    for (int c = 0; c < 4; ++c) {
        const float* xc = x + (size_t)c * 16384 * 256;
        // QKV projections -> chunk-local (n,h,l,e) bf16
        gemm_k<0,1,0,0,0,float,float,u16><<<dim3(4,256), blk, 0, stream>>>(
            xc, Wq, bq, nullptr, nullptr, nullptr, qc, 256, 256);
        gemm_k<0,1,0,0,0,float,float,u16><<<dim3(4,256), blk, 0, stream>>>(
            xc, Wk, bk, nullptr, nullptr, nullptr, kc, 256, 256);
        gemm_k<0,1,0,0,0,float,float,u16><<<dim3(4,256), blk, 0, stream>>>(
            xc, Wv, bv, nullptr, nullptr, nullptr, vc, 256, 256);
        // [qk/16 | QE]
        qkqe_k<<<dim3(4,2,128), blk, 0, stream>>>(qc, kc, Erel, qkc);
        // softmax + skewed S
        softmax_k<<<dim3(4096), blk, 0, stream>>>(qkc, attc);
        // z = att @ v
        av_k<<<dim3(4,2,128), blk, 0, stream>>>(attc, vc, zc);
        // h1pre = z @ Wo + bo + x
        gemm_k<1,0,2,0,0,u16,float,u16><<<dim3(4,256), blk, 0, stream>>>(
            zc, Wo, bo, xc, nullptr, nullptr,
            h1pre + (size_t)c * 16384 * 256, 256, 256);
    }

    // ---- Phase 2: BN1 stats ----
    bnstats_k<<<dim3(2048), blk, 0, stream>>>(h1pre, g1, be1, p1);

    // ---- Phase 3: FFN, chunked over m (4 chunks x 16384 rows) ----
    for (int c = 0; c < 4; ++c) {
        const u16* hc = h1pre + (size_t)c * 16384 * 256;
        // ff1 = leaky(BN1(h1pre) @ W1 + b1) -> bf16
        gemm_k<0,0,1,1,0,u16,float,u16><<<dim3(16,256), blk, 0, stream>>>(
            hc, W1, b1, nullptr, p1, nullptr, ff1, 256, 1024);
        // h2pre = ff1 @ W2 + b2 + BN1(h1pre)
        gemm_k<0,0,2,0,1,u16,u16,u16><<<dim3(4,256), blk, 0, stream>>>(
            ff1, W2, b2, hc, nullptr, p1,
            h2pre + (size_t)c * 16384 * 256, 1024, 256);
    }

    // ---- Phase 4: BN2 stats + encoder projection ----
    bnstats_k<<<dim3(2048), blk, 0, stream>>>(h2pre, g2, be2, p2);
    gemm_k<0,0,0,1,0,u16,float,float><<<dim3(4,1024), blk, 0, stream>>>(
        h2pre, Wenc, benc, nullptr, p2, nullptr, (float*)d_out, 256, 256);
}

// Round 3
// 790.225 us; speedup vs baseline: 2.4177x; 2.4177x over previous
//
#include <hip/hip_runtime.h>
#include <hip/hip_bf16.h>

using u16 = unsigned short;
typedef __attribute__((ext_vector_type(8))) short bf16x8;
typedef __attribute__((ext_vector_type(4))) float f32x4;

static constexpr float EPS_ = 1e-5f;
static constexpr float NEG_ = 0.01f;

__device__ __forceinline__ float bf2f(u16 u) { return __uint_as_float(((unsigned)u) << 16); }
__device__ __forceinline__ u16 f2bf(float f) {
    union { __hip_bfloat16 h; u16 u; } c; c.h = __float2bfloat16(f); return c.u;
}

#define MFMA16(a, b, c) __builtin_amdgcn_mfma_f32_16x16x32_bf16(a, b, c, 0, 0, 0)

// ---------------------------------------------------------------------------
// Shared MFMA core: wave computes 64x64 C-tile. A rows / B^T rows given as 4
// pre-offset pointers each (already + g*8 element offset). k-map = g*8+e for
// both A and B (consistent -> any intra-K permutation cancels).
// ---------------------------------------------------------------------------
template<int K>
__device__ __forceinline__ void mfma_core(
    const u16* __restrict__ a0, const u16* __restrict__ a1,
    const u16* __restrict__ a2, const u16* __restrict__ a3,
    const u16* __restrict__ b0, const u16* __restrict__ b1,
    const u16* __restrict__ b2, const u16* __restrict__ b3,
    f32x4 acc[4][4])
{
    #pragma unroll 2
    for (int k0 = 0; k0 < K; k0 += 32) {
        bf16x8 A0 = *(const bf16x8*)(a0 + k0);
        bf16x8 A1 = *(const bf16x8*)(a1 + k0);
        bf16x8 A2 = *(const bf16x8*)(a2 + k0);
        bf16x8 A3 = *(const bf16x8*)(a3 + k0);
        bf16x8 B0 = *(const bf16x8*)(b0 + k0);
        bf16x8 B1 = *(const bf16x8*)(b1 + k0);
        bf16x8 B2 = *(const bf16x8*)(b2 + k0);
        bf16x8 B3 = *(const bf16x8*)(b3 + k0);
        acc[0][0] = MFMA16(A0, B0, acc[0][0]);
        acc[0][1] = MFMA16(A0, B1, acc[0][1]);
        acc[0][2] = MFMA16(A0, B2, acc[0][2]);
        acc[0][3] = MFMA16(A0, B3, acc[0][3]);
        acc[1][0] = MFMA16(A1, B0, acc[1][0]);
        acc[1][1] = MFMA16(A1, B1, acc[1][1]);
        acc[1][2] = MFMA16(A1, B2, acc[1][2]);
        acc[1][3] = MFMA16(A1, B3, acc[1][3]);
        acc[2][0] = MFMA16(A2, B0, acc[2][0]);
        acc[2][1] = MFMA16(A2, B1, acc[2][1]);
        acc[2][2] = MFMA16(A2, B2, acc[2][2]);
        acc[2][3] = MFMA16(A2, B3, acc[2][3]);
        acc[3][0] = MFMA16(A3, B0, acc[3][0]);
        acc[3][1] = MFMA16(A3, B1, acc[3][1]);
        acc[3][2] = MFMA16(A3, B2, acc[3][2]);
        acc[3][3] = MFMA16(A3, B3, acc[3][3]);
    }
}

__device__ __forceinline__ void zero_acc(f32x4 acc[4][4]) {
    #pragma unroll
    for (int i = 0; i < 4; i++)
        #pragma unroll
        for (int j = 0; j < 4; j++)
            acc[i][j] = (f32x4){0.f, 0.f, 0.f, 0.f};
}

// wave geometry: 4 waves 2x2 over a 128x128 block tile
struct WCtx { int mb; int nb; int g; int r; };
__device__ __forceinline__ WCtx wctx(int m0, int n0) {
    const int tid = threadIdx.x;
    const int w = tid >> 6, lane = tid & 63;
    WCtx c;
    c.g = lane >> 4; c.r = lane & 15;
    c.mb = m0 + (w >> 1) * 64;
    c.nb = n0 + (w & 1) * 64;
    return c;
}

// ---------------------------------------------------------------------------
// Prep kernels
// ---------------------------------------------------------------------------
__global__ __launch_bounds__(256) void cvt_k(const float* __restrict__ in,
                                             u16* __restrict__ out) {
    const size_t i8 = ((size_t)blockIdx.x * 256 + threadIdx.x) * 8;
    const float4 lo = *(const float4*)(in + i8);
    const float4 hi = *(const float4*)(in + i8 + 4);
    ushort4 o0, o1;
    o0.x = f2bf(lo.x); o0.y = f2bf(lo.y); o0.z = f2bf(lo.z); o0.w = f2bf(lo.w);
    o1.x = f2bf(hi.x); o1.y = f2bf(hi.y); o1.z = f2bf(hi.z); o1.w = f2bf(hi.w);
    *(ushort4*)(out + i8) = o0;
    *(ushort4*)(out + i8 + 4) = o1;
}

// out[n][k] (bf16) = in[k][n] (f32); K = 1<<LOGK, N = 1<<LOGN
template<int LOGK, int LOGN>
__global__ __launch_bounds__(256) void tr_k(const float* __restrict__ in,
                                            u16* __restrict__ out) {
    const int t = blockIdx.x * 256 + threadIdx.x;
    const int n = t >> LOGK, k = t & ((1 << LOGK) - 1);
    out[t] = f2bf(in[(k << LOGN) + n]);
}

// ---------------------------------------------------------------------------
// QKV: A = xbf chunk [16384][256]; B = Wt[256][256]; z selects q/k/v.
// q,k -> (n,h,l,e); v -> (n,h,e,l) transposed. grid (2,128,3)
// ---------------------------------------------------------------------------
__global__ __launch_bounds__(256) void qkv_k(
    const u16* __restrict__ xbf,
    const u16* __restrict__ Wqt, const u16* __restrict__ Wkt, const u16* __restrict__ Wvt,
    const float* __restrict__ bq, const float* __restrict__ bk, const float* __restrict__ bv,
    u16* __restrict__ qo, u16* __restrict__ ko, u16* __restrict__ vo)
{
    const int which = blockIdx.z;
    const u16* Wt = which == 0 ? Wqt : (which == 1 ? Wkt : Wvt);
    const float* bias = which == 0 ? bq : (which == 1 ? bk : bv);
    u16* out = which == 0 ? qo : (which == 1 ? ko : vo);
    const WCtx c = wctx(blockIdx.y * 128, blockIdx.x * 128);

    const u16* a0 = xbf + (size_t)(c.mb + 0  + c.r) * 256 + c.g * 8;
    const u16* a1 = xbf + (size_t)(c.mb + 16 + c.r) * 256 + c.g * 8;
    const u16* a2 = xbf + (size_t)(c.mb + 32 + c.r) * 256 + c.g * 8;
    const u16* a3 = xbf + (size_t)(c.mb + 48 + c.r) * 256 + c.g * 8;
    const u16* b0 = Wt + (size_t)(c.nb + 0  + c.r) * 256 + c.g * 8;
    const u16* b1 = Wt + (size_t)(c.nb + 16 + c.r) * 256 + c.g * 8;
    const u16* b2 = Wt + (size_t)(c.nb + 32 + c.r) * 256 + c.g * 8;
    const u16* b3 = Wt + (size_t)(c.nb + 48 + c.r) * 256 + c.g * 8;

    f32x4 acc[4][4]; zero_acc(acc);
    mfma_core<256>(a0, a1, a2, a3, b0, b1, b2, b3, acc);

    #pragma unroll
    for (int fn = 0; fn < 4; fn++) {
        const int n = c.nb + fn * 16 + c.r;
        const float bv4 = bias[n];
        #pragma unroll
        for (int fm = 0; fm < 4; fm++) {
            #pragma unroll
            for (int reg = 0; reg < 4; reg++) {
                const int m = c.mb + fm * 16 + c.g * 4 + reg;
                const float v = acc[fm][fn][reg] + bv4;
                const int nn = m >> 11, lh = m & 2047, l = lh >> 4, hh = lh & 15;
                const size_t oidx = (which == 2)
                    ? ((size_t)(nn * 16 + hh) * 256 + n) * 128 + l
                    : ((size_t)(nn * 16 + hh) * 128 + l) * 256 + n;
                out[oidx] = f2bf(v);
            }
        }
    }
}

// ---------------------------------------------------------------------------
// [qk/16 | QE] batched: A = q[b] 128x256; B rows: n<128 -> k[b][n], n>=128 ->
// Erel[h][n-128]. out bf16 [b*128+i][256]. grid (2,1,128)
// ---------------------------------------------------------------------------
__global__ __launch_bounds__(256) void qkqe_k(
    const u16* __restrict__ q, const u16* __restrict__ kc,
    const u16* __restrict__ erel, u16* __restrict__ out)
{
    const int b = blockIdx.z, h = b & 15;
    const int n0 = blockIdx.x * 128;
    const WCtx c = wctx(0, n0);
    const u16* ab = q + (size_t)b * 128 * 256;
    const u16* a0 = ab + (size_t)(c.mb + 0  + c.r) * 256 + c.g * 8;
    const u16* a1 = ab + (size_t)(c.mb + 16 + c.r) * 256 + c.g * 8;
    const u16* a2 = ab + (size_t)(c.mb + 32 + c.r) * 256 + c.g * 8;
    const u16* a3 = ab + (size_t)(c.mb + 48 + c.r) * 256 + c.g * 8;
    const u16* bb = (n0 == 0) ? (kc + (size_t)b * 128 * 256)
                              : (erel + (size_t)h * 128 * 256);
    const int jb = (n0 == 0) ? c.nb : (c.nb - 128);
    const u16* b0 = bb + (size_t)(jb + 0  + c.r) * 256 + c.g * 8;
    const u16* b1 = bb + (size_t)(jb + 16 + c.r) * 256 + c.g * 8;
    const u16* b2 = bb + (size_t)(jb + 32 + c.r) * 256 + c.g * 8;
    const u16* b3 = bb + (size_t)(jb + 48 + c.r) * 256 + c.g * 8;

    f32x4 acc[4][4]; zero_acc(acc);
    mfma_core<256>(a0, a1, a2, a3, b0, b1, b2, b3, acc);

    const float scale = (n0 == 0) ? 0.0625f : 1.0f;
    #pragma unroll
    for (int fm = 0; fm < 4; fm++)
        #pragma unroll
        for (int fn = 0; fn < 4; fn++)
            #pragma unroll
            for (int reg = 0; reg < 4; reg++) {
                const int m = c.mb + fm * 16 + c.g * 4 + reg;
                const int n = c.nb + fn * 16 + c.r;
                out[((size_t)b * 128 + m) * 256 + n] = f2bf(acc[fm][fn][reg] * scale);
            }
}

// ---------------------------------------------------------------------------
// softmax + skewed-S add (bf16 in/out). S[i,c] = QE[i][127-i+c] for c<=i.
// ---------------------------------------------------------------------------
__global__ __launch_bounds__(256) void softmax_k(
    const u16* __restrict__ qk, u16* __restrict__ att)
{
    const int r = blockIdx.x * 4 + (threadIdx.x >> 6);
    const int lane = threadIdx.x & 63;
    const int i = r & 127;
    const u16* row = qk + (size_t)r * 256;
    const float x0 = bf2f(row[lane]), x1 = bf2f(row[lane + 64]);
    float mx = fmaxf(x0, x1);
    #pragma unroll
    for (int o = 32; o; o >>= 1) mx = fmaxf(mx, __shfl_xor(mx, o));
    const float e0 = __expf(x0 - mx), e1 = __expf(x1 - mx);
    float s = e0 + e1;
    #pragma unroll
    for (int o = 32; o; o >>= 1) s += __shfl_xor(s, o);
    const float rinv = 1.0f / s;
    const float s0 = (lane <= i) ? bf2f(row[128 + 127 - i + lane]) : 0.f;
    const float s1 = (lane + 64 <= i) ? bf2f(row[128 + 127 - i + lane + 64]) : 0.f;
    att[(size_t)r * 128 + lane] = f2bf(e0 * rinv + s0);
    att[(size_t)r * 128 + lane + 64] = f2bf(e1 * rinv + s1);
}

// ---------------------------------------------------------------------------
// z = att[b] (128x128) @ v[b] (via vT [e][l]); out zc in m-order (chunk-local)
// grid (2,1,128)
// ---------------------------------------------------------------------------
__global__ __launch_bounds__(256) void av_k(
    const u16* __restrict__ att, const u16* __restrict__ vT,
    u16* __restrict__ zc)
{
    const int b = blockIdx.z;
    const WCtx c = wctx(0, blockIdx.x * 128);
    const u16* ab = att + (size_t)b * 128 * 128;
    const u16* a0 = ab + (size_t)(c.mb + 0  + c.r) * 128 + c.g * 8;
    const u16* a1 = ab + (size_t)(c.mb + 16 + c.r) * 128 + c.g * 8;
    const u16* a2 = ab + (size_t)(c.mb + 32 + c.r) * 128 + c.g * 8;
    const u16* a3 = ab + (size_t)(c.mb + 48 + c.r) * 128 + c.g * 8;
    const u16* bb = vT + (size_t)b * 256 * 128;
    const u16* b0 = bb + (size_t)(c.nb + 0  + c.r) * 128 + c.g * 8;
    const u16* b1 = bb + (size_t)(c.nb + 16 + c.r) * 128 + c.g * 8;
    const u16* b2 = bb + (size_t)(c.nb + 32 + c.r) * 128 + c.g * 8;
    const u16* b3 = bb + (size_t)(c.nb + 48 + c.r) * 128 + c.g * 8;

    f32x4 acc[4][4]; zero_acc(acc);
    mfma_core<128>(a0, a1, a2, a3, b0, b1, b2, b3, acc);

    const int nloc = b >> 4, hh = b & 15;
    #pragma unroll
    for (int fm = 0; fm < 4; fm++)
        #pragma unroll
        for (int fn = 0; fn < 4; fn++)
            #pragma unroll
            for (int reg = 0; reg < 4; reg++) {
                const int i = c.mb + fm * 16 + c.g * 4 + reg;   // query row
                const int n = c.nb + fn * 16 + c.r;             // e
                zc[((size_t)(nloc * 2048 + i * 16 + hh)) * 256 + n] =
                    f2bf(acc[fm][fn][reg]);
            }
}

// ---------------------------------------------------------------------------
// Generic GEMM: out[m][Nn] = A[m][K] @ Wt^T + bias (+epilogue)
// EPI: 0 plain; 1 leaky; 2 +res f32; 3 +res bf16.  TO: u16 or float.
// ---------------------------------------------------------------------------
template<int K, int Nn, int EPI, typename TR, typename TO>
__global__ __launch_bounds__(256) void gemm_k(
    const u16* __restrict__ A, const u16* __restrict__ Wt,
    const float* __restrict__ bias, const TR* __restrict__ res,
    TO* __restrict__ out)
{
    const WCtx c = wctx(blockIdx.y * 128, blockIdx.x * 128);
    const u16* a0 = A + (size_t)(c.mb + 0  + c.r) * K + c.g * 8;
    const u16* a1 = A + (size_t)(c.mb + 16 + c.r) * K + c.g * 8;
    const u16* a2 = A + (size_t)(c.mb + 32 + c.r) * K + c.g * 8;
    const u16* a3 = A + (size_t)(c.mb + 48 + c.r) * K + c.g * 8;
    const u16* b0 = Wt + (size_t)(c.nb + 0  + c.r) * K + c.g * 8;
    const u16* b1 = Wt + (size_t)(c.nb + 16 + c.r) * K + c.g * 8;
    const u16* b2 = Wt + (size_t)(c.nb + 32 + c.r) * K + c.g * 8;
    const u16* b3 = Wt + (size_t)(c.nb + 48 + c.r) * K + c.g * 8;

    f32x4 acc[4][4]; zero_acc(acc);
    mfma_core<K>(a0, a1, a2, a3, b0, b1, b2, b3, acc);

    #pragma unroll
    for (int fn = 0; fn < 4; fn++) {
        const int n = c.nb + fn * 16 + c.r;
        const float bv4 = bias[n];
        #pragma unroll
        for (int fm = 0; fm < 4; fm++) {
            #pragma unroll
            for (int reg = 0; reg < 4; reg++) {
                const int m = c.mb + fm * 16 + c.g * 4 + reg;
                float v = acc[fm][fn][reg] + bv4;
                if constexpr (EPI == 2)
                    v += ((const float*)res)[(size_t)m * Nn + n];
                if constexpr (EPI == 3)
                    v += bf2f(((const u16*)res)[(size_t)m * Nn + n]);
                if constexpr (EPI == 1)
                    v = v >= 0.f ? v : NEG_ * v;
                if constexpr (sizeof(TO) == 2) out[(size_t)m * Nn + n] = f2bf(v);
                else                           out[(size_t)m * Nn + n] = v;
            }
        }
    }
}

// ---------------------------------------------------------------------------
// batchnorm stats over (n, e) per channel c (bf16 input, full 65536 rows)
// ---------------------------------------------------------------------------
__global__ __launch_bounds__(256) void bnstats_k(
    const u16* __restrict__ x, const float* __restrict__ g,
    const float* __restrict__ be, float2* __restrict__ params)
{
    const int c = blockIdx.x, tid = threadIdx.x;
    float s = 0.f, s2 = 0.f;
    #pragma unroll 4
    for (int n = 0; n < 32; n++) {
        const float v = bf2f(x[((size_t)n * 2048 + c) * 256 + tid]);
        s += v; s2 += v * v;
    }
    #pragma unroll
    for (int o = 32; o; o >>= 1) { s += __shfl_xor(s, o); s2 += __shfl_xor(s2, o); }
    __shared__ float rs[4], rs2[4];
    const int w = tid >> 6;
    if ((tid & 63) == 0) { rs[w] = s; rs2[w] = s2; }
    __syncthreads();
    if (tid == 0) {
        s  = rs[0] + rs[1] + rs[2] + rs[3];
        s2 = rs2[0] + rs2[1] + rs2[2] + rs2[3];
        const float mean = s / 8192.f;
        const float var = s2 / 8192.f - mean * mean;
        const float a = g[c] * rsqrtf(var + EPS_);
        params[c] = make_float2(a, be[c] - mean * a);
    }
}

__global__ __launch_bounds__(256) void bnapply_k(
    const u16* __restrict__ in, const float2* __restrict__ p,
    u16* __restrict__ out)
{
    const size_t idx = (size_t)blockIdx.x * 256 + threadIdx.x;  // ushort8 unit
    const int c = (int)((idx >> 5) & 2047);
    const float2 pp = p[c];
    const ushort4 v0 = ((const ushort4*)(in + idx * 8))[0];
    const ushort4 v1 = ((const ushort4*)(in + idx * 8))[1];
    ushort4 o0, o1;
    o0.x = f2bf(bf2f(v0.x) * pp.x + pp.y);
    o0.y = f2bf(bf2f(v0.y) * pp.x + pp.y);
    o0.z = f2bf(bf2f(v0.z) * pp.x + pp.y);
    o0.w = f2bf(bf2f(v0.w) * pp.x + pp.y);
    o1.x = f2bf(bf2f(v1.x) * pp.x + pp.y);
    o1.y = f2bf(bf2f(v1.y) * pp.x + pp.y);
    o1.z = f2bf(bf2f(v1.z) * pp.x + pp.y);
    o1.w = f2bf(bf2f(v1.w) * pp.x + pp.y);
    ((ushort4*)(out + idx * 8))[0] = o0;
    ((ushort4*)(out + idx * 8))[1] = o1;
}

// ---------------------------------------------------------------------------
extern "C" void kernel_launch(void* const* d_in, const int* in_sizes, int n_in,
                              void* d_out, int out_size, void* d_ws, size_t ws_size,
                              hipStream_t stream)
{
    const float* x    = (const float*)d_in[0];
    const float* Wq   = (const float*)d_in[1];
    const float* bq   = (const float*)d_in[2];
    const float* Wk   = (const float*)d_in[3];
    const float* bk   = (const float*)d_in[4];
    const float* Wv   = (const float*)d_in[5];
    const float* bv   = (const float*)d_in[6];
    const float* Erel = (const float*)d_in[7];
    const float* Wo   = (const float*)d_in[8];
    const float* bo   = (const float*)d_in[9];
    const float* g1   = (const float*)d_in[10];
    const float* be1  = (const float*)d_in[11];
    const float* g2   = (const float*)d_in[12];
    const float* be2  = (const float*)d_in[13];
    const float* W1   = (const float*)d_in[14];
    const float* b1   = (const float*)d_in[15];
    const float* W2   = (const float*)d_in[16];
    const float* b2   = (const float*)d_in[17];
    const float* Wenc = (const float*)d_in[18];
    const float* benc = (const float*)d_in[19];

    char* ws = (char*)d_ws;
    const size_t MB = 1ull << 20;
    const size_t KB = 1024;
    // region 0: xbf (prep+attn) -> ff1 (ffn) -> h2n (enc)
    u16* xbf  = (u16*)(ws + 0 * MB);
    u16* ff1  = (u16*)(ws + 0 * MB);
    u16* h2n  = (u16*)(ws + 0 * MB);
    // region 1: h1pre -> h2pre
    u16* h1pre = (u16*)(ws + 32 * MB);
    u16* h2pre = (u16*)(ws + 32 * MB);
    // region 2: attention scratch (dead after attn) -> h1n
    u16* qc   = (u16*)(ws + 64 * MB);   // 8 MB
    u16* kcb  = (u16*)(ws + 72 * MB);   // 8 MB
    u16* vT   = (u16*)(ws + 80 * MB);   // 8 MB
    u16* qkcb = (u16*)(ws + 88 * MB);   // 8 MB
    u16* attb = (u16*)(ws + 96 * MB);   // 4 MB
    u16* zc   = (u16*)(ws + 100 * MB);  // 8 MB
    u16* h1n  = (u16*)(ws + 64 * MB);   // 32 MB (after attention)
    // weights (bf16, transposed) + params
    u16* Wqt   = (u16*)(ws + 108 * MB);
    u16* Wkt   = (u16*)(ws + 108 * MB + 128 * KB);
    u16* Wvt   = (u16*)(ws + 108 * MB + 256 * KB);
    u16* Wot   = (u16*)(ws + 108 * MB + 384 * KB);
    u16* Wenct = (u16*)(ws + 108 * MB + 512 * KB);
    u16* W1t   = (u16*)(ws + 108 * MB + 640 * KB);   // 512 KB
    u16* W2t   = (u16*)(ws + 108 * MB + 1152 * KB);  // 512 KB
    u16* Erelb = (u16*)(ws + 108 * MB + 1664 * KB);  // 1 MB
    float2* p1 = (float2*)(ws + 111 * MB);
    float2* p2 = (float2*)(ws + 111 * MB + 16 * KB);

    const dim3 blk(256);
    const size_t CH = 16384 * 256;   // chunk elems

    // ---- prep: conversions + weight transposes ----
    cvt_k<<<dim3(8192), blk, 0, stream>>>(x, xbf);                 // 16.7M elems
    cvt_k<<<dim3(256), blk, 0, stream>>>(Erel, Erelb);             // 524288 elems
    tr_k<8, 8><<<dim3(256), blk, 0, stream>>>(Wq, Wqt);
    tr_k<8, 8><<<dim3(256), blk, 0, stream>>>(Wk, Wkt);
    tr_k<8, 8><<<dim3(256), blk, 0, stream>>>(Wv, Wvt);
    tr_k<8, 8><<<dim3(256), blk, 0, stream>>>(Wo, Wot);
    tr_k<8, 8><<<dim3(256), blk, 0, stream>>>(Wenc, Wenct);
    tr_k<8, 10><<<dim3(1024), blk, 0, stream>>>(W1, W1t);          // [256][1024] -> [1024][256]
    tr_k<10, 8><<<dim3(1024), blk, 0, stream>>>(W2, W2t);          // [1024][256] -> [256][1024]

    // ---- attention (4 chunks of 8 n) ----
    for (int c = 0; c < 4; ++c) {
        qkv_k<<<dim3(2, 128, 3), blk, 0, stream>>>(
            xbf + (size_t)c * CH, Wqt, Wkt, Wvt, bq, bk, bv, qc, kcb, vT);
        qkqe_k<<<dim3(2, 1, 128), blk, 0, stream>>>(qc, kcb, Erelb, qkcb);
        softmax_k<<<dim3(4096), blk, 0, stream>>>(qkcb, attb);
        av_k<<<dim3(2, 1, 128), blk, 0, stream>>>(attb, vT, zc);
        gemm_k<256, 256, 2, float, u16><<<dim3(2, 128), blk, 0, stream>>>(
            zc, Wot, bo, x + (size_t)c * CH, h1pre + (size_t)c * CH);
    }

    // ---- BN1 ----
    bnstats_k<<<dim3(2048), blk, 0, stream>>>(h1pre, g1, be1, p1);
    bnapply_k<<<dim3(8192), blk, 0, stream>>>(h1pre, p1, h1n);

    // ---- FFN (4 chunks) ----
    for (int c = 0; c < 4; ++c) {
        gemm_k<256, 1024, 1, float, u16><<<dim3(8, 128), blk, 0, stream>>>(
            h1n + (size_t)c * CH, W1t, b1, nullptr, ff1);
        gemm_k<1024, 256, 3, u16, u16><<<dim3(2, 128), blk, 0, stream>>>(
            ff1, W2t, b2, h1n + (size_t)c * CH, h2pre + (size_t)c * CH);
    }

    // ---- BN2 + encoder ----
    bnstats_k<<<dim3(2048), blk, 0, stream>>>(h2pre, g2, be2, p2);
    bnapply_k<<<dim3(8192), blk, 0, stream>>>(h2pre, p2, h2n);
    gemm_k<256, 256, 0, float, float><<<dim3(2, 512), blk, 0, stream>>>(
        h2n, Wenct, benc, (const float*)nullptr, (float*)d_out);
}

// Round 4
// 530.209 us; speedup vs baseline: 3.6033x; 1.4904x over previous
//
#include <hip/hip_runtime.h>
#include <hip/hip_bf16.h>

using u16 = unsigned short;
typedef __attribute__((ext_vector_type(8))) short bf16x8;
typedef __attribute__((ext_vector_type(4))) float f32x4;

static constexpr float EPS_ = 1e-5f;
static constexpr float NEG_ = 0.01f;

__device__ __forceinline__ float bf2f(u16 u) { return __uint_as_float(((unsigned)u) << 16); }
__device__ __forceinline__ u16 f2bf(float f) {
    union { __hip_bfloat16 h; u16 u; } c; c.h = __float2bfloat16(f); return c.u;
}

#define MFMA16(a, b, c) __builtin_amdgcn_mfma_f32_16x16x32_bf16(a, b, c, 0, 0, 0)

// async global->LDS, 16B per lane (wave-uniform LDS base, per-lane global addr)
__device__ __forceinline__ void gload16(const u16* g, u16* l) {
    __builtin_amdgcn_global_load_lds(
        (__attribute__((address_space(1))) void*)(u16*)g,
        (__attribute__((address_space(3))) void*)l, 16, 0, 0);
}

__device__ __forceinline__ void zero_acc(f32x4 acc[4][4]) {
    #pragma unroll
    for (int i = 0; i < 4; i++)
        #pragma unroll
        for (int j = 0; j < 4; j++)
            acc[i][j] = (f32x4){0.f, 0.f, 0.f, 0.f};
}

// ---------------------------------------------------------------------------
// m97-style core: block computes 128x128 C-tile, 4 waves in 2x2, BK=64.
// A block base Ag: rows m0..m0+127 of [*][lda]; B block base Bg: rows
// n0..n0+127 of B^T [*][ldb]. Single 32KB LDS buffer, 2 barriers / K-tile.
// Fragment k-map = kt + kk*32 + g*8 .. +7, identical for A and B.
// ---------------------------------------------------------------------------
__device__ __forceinline__ void lds_core(
    const u16* __restrict__ Ag, int lda,
    const u16* __restrict__ Bg, int ldb, int K,
    u16* As, u16* Bs, f32x4 acc[4][4])
{
    const int tid = threadIdx.x;
    const int w = tid >> 6, lane = tid & 63;
    const int g = lane >> 4, r = lane & 15;
    const int wm = (w >> 1) * 64, wn = (w & 1) * 64;

    for (int kt = 0; kt < K; kt += 64) {
        #pragma unroll
        for (int j = 0; j < 4; j++) {
            const int ubase = (w * 4 + j) * 64;       // 16B-unit base (wave-uniform)
            const int u = ubase + lane;               // this lane's unit
            const int row = u >> 3, cb = (u & 7) * 8; // row 0..127, col 0..56
            gload16(Ag + (size_t)row * lda + kt + cb, As + ubase * 8);
            gload16(Bg + (size_t)row * ldb + kt + cb, Bs + ubase * 8);
        }
        __syncthreads();   // drains vmcnt before barrier (compiler-emitted)
        #pragma unroll
        for (int kk = 0; kk < 2; kk++) {
            bf16x8 af[4], bfr[4];
            #pragma unroll
            for (int f = 0; f < 4; f++) {
                af[f]  = *(const bf16x8*)(As + (wm + f * 16 + r) * 64 + kk * 32 + g * 8);
                bfr[f] = *(const bf16x8*)(Bs + (wn + f * 16 + r) * 64 + kk * 32 + g * 8);
            }
            #pragma unroll
            for (int i = 0; i < 4; i++)
                #pragma unroll
                for (int j = 0; j < 4; j++)
                    acc[i][j] = MFMA16(af[i], bfr[j], acc[i][j]);
        }
        __syncthreads();
    }
}

// wave geometry for epilogue (must match lds_core)
struct WCtx { int mb; int nb; int g; int r; };
__device__ __forceinline__ WCtx wctx(int m0, int n0) {
    const int tid = threadIdx.x;
    const int w = tid >> 6, lane = tid & 63;
    WCtx c;
    c.g = lane >> 4; c.r = lane & 15;
    c.mb = m0 + (w >> 1) * 64;
    c.nb = n0 + (w & 1) * 64;
    return c;
}

// ---------------------------------------------------------------------------
// Prep kernels
// ---------------------------------------------------------------------------
__global__ __launch_bounds__(256) void cvt_k(const float* __restrict__ in,
                                             u16* __restrict__ out) {
    const size_t i8 = ((size_t)blockIdx.x * 256 + threadIdx.x) * 8;
    const float4 lo = *(const float4*)(in + i8);
    const float4 hi = *(const float4*)(in + i8 + 4);
    ushort4 o0, o1;
    o0.x = f2bf(lo.x); o0.y = f2bf(lo.y); o0.z = f2bf(lo.z); o0.w = f2bf(lo.w);
    o1.x = f2bf(hi.x); o1.y = f2bf(hi.y); o1.z = f2bf(hi.z); o1.w = f2bf(hi.w);
    *(ushort4*)(out + i8) = o0;
    *(ushort4*)(out + i8 + 4) = o1;
}

// out[n][k] (bf16) = in[k][n] (f32); K = 1<<LOGK, N = 1<<LOGN
template<int LOGK, int LOGN>
__global__ __launch_bounds__(256) void tr_k(const float* __restrict__ in,
                                            u16* __restrict__ out) {
    const int t = blockIdx.x * 256 + threadIdx.x;
    const int n = t >> LOGK, k = t & ((1 << LOGK) - 1);
    out[t] = f2bf(in[(k << LOGN) + n]);
}

// ---------------------------------------------------------------------------
// QKV: A = xbf chunk [16384][256]; B = Wt[256][256]; z selects q/k/v.
// q,k -> (n,h,l,e); v -> (n,h,e,l) transposed. grid (2,128,3)
// ---------------------------------------------------------------------------
__global__ __launch_bounds__(256) void qkv_k(
    const u16* __restrict__ xbf,
    const u16* __restrict__ Wqt, const u16* __restrict__ Wkt, const u16* __restrict__ Wvt,
    const float* __restrict__ bq, const float* __restrict__ bk, const float* __restrict__ bv,
    u16* __restrict__ qo, u16* __restrict__ ko, u16* __restrict__ vo)
{
    __shared__ __align__(16) u16 As[128 * 64];
    __shared__ __align__(16) u16 Bs[128 * 64];
    const int which = blockIdx.z;
    const u16* Wt = which == 0 ? Wqt : (which == 1 ? Wkt : Wvt);
    const float* bias = which == 0 ? bq : (which == 1 ? bk : bv);
    u16* out = which == 0 ? qo : (which == 1 ? ko : vo);
    const int m0 = blockIdx.y * 128, n0 = blockIdx.x * 128;

    f32x4 acc[4][4]; zero_acc(acc);
    lds_core(xbf + (size_t)m0 * 256, 256, Wt + (size_t)n0 * 256, 256, 256, As, Bs, acc);

    const WCtx c = wctx(m0, n0);
    #pragma unroll
    for (int fn = 0; fn < 4; fn++) {
        const int n = c.nb + fn * 16 + c.r;
        const float bv4 = bias[n];
        #pragma unroll
        for (int fm = 0; fm < 4; fm++) {
            #pragma unroll
            for (int reg = 0; reg < 4; reg++) {
                const int m = c.mb + fm * 16 + c.g * 4 + reg;
                const float v = acc[fm][fn][reg] + bv4;
                const int nn = m >> 11, lh = m & 2047, l = lh >> 4, hh = lh & 15;
                const size_t oidx = (which == 2)
                    ? ((size_t)(nn * 16 + hh) * 256 + n) * 128 + l
                    : ((size_t)(nn * 16 + hh) * 128 + l) * 256 + n;
                out[oidx] = f2bf(v);
            }
        }
    }
}

// ---------------------------------------------------------------------------
// [qk/16 | QE] batched: A = q[b] 128x256; B: x=0 -> k[b], x=1 -> Erel[h].
// out bf16 [b*128+i][256]. grid (2,1,128)
// ---------------------------------------------------------------------------
__global__ __launch_bounds__(256) void qkqe_k(
    const u16* __restrict__ q, const u16* __restrict__ kc,
    const u16* __restrict__ erel, u16* __restrict__ out)
{
    __shared__ __align__(16) u16 As[128 * 64];
    __shared__ __align__(16) u16 Bs[128 * 64];
    const int b = blockIdx.z, h = b & 15;
    const int n0 = blockIdx.x * 128;
    const u16* Ag = q + (size_t)b * 128 * 256;
    const u16* Bg = (n0 == 0) ? (kc + (size_t)b * 128 * 256)
                              : (erel + (size_t)h * 128 * 256);

    f32x4 acc[4][4]; zero_acc(acc);
    lds_core(Ag, 256, Bg, 256, 256, As, Bs, acc);

    const WCtx c = wctx(0, n0);
    const float scale = (n0 == 0) ? 0.0625f : 1.0f;
    #pragma unroll
    for (int fm = 0; fm < 4; fm++)
        #pragma unroll
        for (int fn = 0; fn < 4; fn++)
            #pragma unroll
            for (int reg = 0; reg < 4; reg++) {
                const int m = c.mb + fm * 16 + c.g * 4 + reg;
                const int n = c.nb + fn * 16 + c.r;
                out[((size_t)b * 128 + m) * 256 + n] = f2bf(acc[fm][fn][reg] * scale);
            }
}

// ---------------------------------------------------------------------------
// softmax + skewed-S add (bf16 in/out). S[i,c] = QE[i][127-i+c] for c<=i.
// ---------------------------------------------------------------------------
__global__ __launch_bounds__(256) void softmax_k(
    const u16* __restrict__ qk, u16* __restrict__ att)
{
    const int r = blockIdx.x * 4 + (threadIdx.x >> 6);
    const int lane = threadIdx.x & 63;
    const int i = r & 127;
    const u16* row = qk + (size_t)r * 256;
    const float x0 = bf2f(row[lane]), x1 = bf2f(row[lane + 64]);
    float mx = fmaxf(x0, x1);
    #pragma unroll
    for (int o = 32; o; o >>= 1) mx = fmaxf(mx, __shfl_xor(mx, o));
    const float e0 = __expf(x0 - mx), e1 = __expf(x1 - mx);
    float s = e0 + e1;
    #pragma unroll
    for (int o = 32; o; o >>= 1) s += __shfl_xor(s, o);
    const float rinv = 1.0f / s;
    const float s0 = (lane <= i) ? bf2f(row[128 + 127 - i + lane]) : 0.f;
    const float s1 = (lane + 64 <= i) ? bf2f(row[128 + 127 - i + lane + 64]) : 0.f;
    att[(size_t)r * 128 + lane] = f2bf(e0 * rinv + s0);
    att[(size_t)r * 128 + lane + 64] = f2bf(e1 * rinv + s1);
}

// ---------------------------------------------------------------------------
// z = att[b] (128x128) @ v[b] (via vT [e][l]); out zc in m-order (chunk-local)
// grid (2,1,128)
// ---------------------------------------------------------------------------
__global__ __launch_bounds__(256) void av_k(
    const u16* __restrict__ att, const u16* __restrict__ vT,
    u16* __restrict__ zc)
{
    __shared__ __align__(16) u16 As[128 * 64];
    __shared__ __align__(16) u16 Bs[128 * 64];
    const int b = blockIdx.z;
    const int n0 = blockIdx.x * 128;
    const u16* Ag = att + (size_t)b * 128 * 128;
    const u16* Bg = vT + (size_t)b * 256 * 128 + (size_t)n0 * 128;

    f32x4 acc[4][4]; zero_acc(acc);
    lds_core(Ag, 128, Bg, 128, 128, As, Bs, acc);

    const WCtx c = wctx(0, n0);
    const int nloc = b >> 4, hh = b & 15;
    #pragma unroll
    for (int fm = 0; fm < 4; fm++)
        #pragma unroll
        for (int fn = 0; fn < 4; fn++)
            #pragma unroll
            for (int reg = 0; reg < 4; reg++) {
                const int i = c.mb + fm * 16 + c.g * 4 + reg;   // query row
                const int n = c.nb + fn * 16 + c.r;             // e
                zc[((size_t)(nloc * 2048 + i * 16 + hh)) * 256 + n] =
                    f2bf(acc[fm][fn][reg]);
            }
}

// ---------------------------------------------------------------------------
// Generic GEMM: out[m][Nn] = A[m][K] @ Wt^T + bias (+epilogue)
// EPI: 0 plain; 1 leaky; 2 +res f32; 3 +res bf16.  TO: u16 or float.
// grid (Nn/128, M/128)
// ---------------------------------------------------------------------------
template<int K, int Nn, int EPI, typename TR, typename TO>
__global__ __launch_bounds__(256) void gemm_k(
    const u16* __restrict__ A, const u16* __restrict__ Wt,
    const float* __restrict__ bias, const TR* __restrict__ res,
    TO* __restrict__ out)
{
    __shared__ __align__(16) u16 As[128 * 64];
    __shared__ __align__(16) u16 Bs[128 * 64];
    const int m0 = blockIdx.y * 128, n0 = blockIdx.x * 128;

    f32x4 acc[4][4]; zero_acc(acc);
    lds_core(A + (size_t)m0 * K, K, Wt + (size_t)n0 * K, K, K, As, Bs, acc);

    const WCtx c = wctx(m0, n0);
    #pragma unroll
    for (int fn = 0; fn < 4; fn++) {
        const int n = c.nb + fn * 16 + c.r;
        const float bv4 = bias[n];
        #pragma unroll
        for (int fm = 0; fm < 4; fm++) {
            #pragma unroll
            for (int reg = 0; reg < 4; reg++) {
                const int m = c.mb + fm * 16 + c.g * 4 + reg;
                float v = acc[fm][fn][reg] + bv4;
                if constexpr (EPI == 2)
                    v += ((const float*)res)[(size_t)m * Nn + n];
                if constexpr (EPI == 3)
                    v += bf2f(((const u16*)res)[(size_t)m * Nn + n]);
                if constexpr (EPI == 1)
                    v = v >= 0.f ? v : NEG_ * v;
                if constexpr (sizeof(TO) == 2) out[(size_t)m * Nn + n] = f2bf(v);
                else                           out[(size_t)m * Nn + n] = v;
            }
        }
    }
}

// ---------------------------------------------------------------------------
// batchnorm stats over (n, e) per channel c (bf16 input, full 65536 rows)
// ---------------------------------------------------------------------------
__global__ __launch_bounds__(256) void bnstats_k(
    const u16* __restrict__ x, const float* __restrict__ g,
    const float* __restrict__ be, float2* __restrict__ params)
{
    const int c = blockIdx.x, tid = threadIdx.x;
    float s = 0.f, s2 = 0.f;
    #pragma unroll 4
    for (int n = 0; n < 32; n++) {
        const float v = bf2f(x[((size_t)n * 2048 + c) * 256 + tid]);
        s += v; s2 += v * v;
    }
    #pragma unroll
    for (int o = 32; o; o >>= 1) { s += __shfl_xor(s, o); s2 += __shfl_xor(s2, o); }
    __shared__ float rs[4], rs2[4];
    const int w = tid >> 6;
    if ((tid & 63) == 0) { rs[w] = s; rs2[w] = s2; }
    __syncthreads();
    if (tid == 0) {
        s  = rs[0] + rs[1] + rs[2] + rs[3];
        s2 = rs2[0] + rs2[1] + rs2[2] + rs2[3];
        const float mean = s / 8192.f;
        const float var = s2 / 8192.f - mean * mean;
        const float a = g[c] * rsqrtf(var + EPS_);
        params[c] = make_float2(a, be[c] - mean * a);
    }
}

__global__ __launch_bounds__(256) void bnapply_k(
    const u16* __restrict__ in, const float2* __restrict__ p,
    u16* __restrict__ out)
{
    const size_t idx = (size_t)blockIdx.x * 256 + threadIdx.x;  // ushort8 unit
    const int c = (int)((idx >> 5) & 2047);
    const float2 pp = p[c];
    const ushort4 v0 = ((const ushort4*)(in + idx * 8))[0];
    const ushort4 v1 = ((const ushort4*)(in + idx * 8))[1];
    ushort4 o0, o1;
    o0.x = f2bf(bf2f(v0.x) * pp.x + pp.y);
    o0.y = f2bf(bf2f(v0.y) * pp.x + pp.y);
    o0.z = f2bf(bf2f(v0.z) * pp.x + pp.y);
    o0.w = f2bf(bf2f(v0.w) * pp.x + pp.y);
    o1.x = f2bf(bf2f(v1.x) * pp.x + pp.y);
    o1.y = f2bf(bf2f(v1.y) * pp.x + pp.y);
    o1.z = f2bf(bf2f(v1.z) * pp.x + pp.y);
    o1.w = f2bf(bf2f(v1.w) * pp.x + pp.y);
    ((ushort4*)(out + idx * 8))[0] = o0;
    ((ushort4*)(out + idx * 8))[1] = o1;
}

// ---------------------------------------------------------------------------
extern "C" void kernel_launch(void* const* d_in, const int* in_sizes, int n_in,
                              void* d_out, int out_size, void* d_ws, size_t ws_size,
                              hipStream_t stream)
{
    const float* x    = (const float*)d_in[0];
    const float* Wq   = (const float*)d_in[1];
    const float* bq   = (const float*)d_in[2];
    const float* Wk   = (const float*)d_in[3];
    const float* bk   = (const float*)d_in[4];
    const float* Wv   = (const float*)d_in[5];
    const float* bv   = (const float*)d_in[6];
    const float* Erel = (const float*)d_in[7];
    const float* Wo   = (const float*)d_in[8];
    const float* bo   = (const float*)d_in[9];
    const float* g1   = (const float*)d_in[10];
    const float* be1  = (const float*)d_in[11];
    const float* g2   = (const float*)d_in[12];
    const float* be2  = (const float*)d_in[13];
    const float* W1   = (const float*)d_in[14];
    const float* b1   = (const float*)d_in[15];
    const float* W2   = (const float*)d_in[16];
    const float* b2   = (const float*)d_in[17];
    const float* Wenc = (const float*)d_in[18];
    const float* benc = (const float*)d_in[19];

    char* ws = (char*)d_ws;
    const size_t MB = 1ull << 20;
    const size_t KB = 1024;
    // region 0: xbf (prep+attn) -> ff1 (ffn) -> h2n (enc)
    u16* xbf  = (u16*)(ws + 0 * MB);
    u16* ff1  = (u16*)(ws + 0 * MB);
    u16* h2n  = (u16*)(ws + 0 * MB);
    // region 1: h1pre -> h2pre
    u16* h1pre = (u16*)(ws + 32 * MB);
    u16* h2pre = (u16*)(ws + 32 * MB);
    // region 2: attention scratch (dead after attn) -> h1n
    u16* qc   = (u16*)(ws + 64 * MB);   // 8 MB
    u16* kcb  = (u16*)(ws + 72 * MB);   // 8 MB
    u16* vT   = (u16*)(ws + 80 * MB);   // 8 MB
    u16* qkcb = (u16*)(ws + 88 * MB);   // 8 MB
    u16* attb = (u16*)(ws + 96 * MB);   // 4 MB
    u16* zc   = (u16*)(ws + 100 * MB);  // 8 MB
    u16* h1n  = (u16*)(ws + 64 * MB);   // 32 MB (after attention)
    // weights (bf16, transposed) + params
    u16* Wqt   = (u16*)(ws + 108 * MB);
    u16* Wkt   = (u16*)(ws + 108 * MB + 128 * KB);
    u16* Wvt   = (u16*)(ws + 108 * MB + 256 * KB);
    u16* Wot   = (u16*)(ws + 108 * MB + 384 * KB);
    u16* Wenct = (u16*)(ws + 108 * MB + 512 * KB);
    u16* W1t   = (u16*)(ws + 108 * MB + 640 * KB);   // 512 KB
    u16* W2t   = (u16*)(ws + 108 * MB + 1152 * KB);  // 512 KB
    u16* Erelb = (u16*)(ws + 108 * MB + 1664 * KB);  // 1 MB
    float2* p1 = (float2*)(ws + 111 * MB);
    float2* p2 = (float2*)(ws + 111 * MB + 16 * KB);

    const dim3 blk(256);
    const size_t CH = 16384 * 256;   // chunk elems

    // ---- prep: conversions + weight transposes ----
    cvt_k<<<dim3(8192), blk, 0, stream>>>(x, xbf);
    cvt_k<<<dim3(256), blk, 0, stream>>>(Erel, Erelb);
    tr_k<8, 8><<<dim3(256), blk, 0, stream>>>(Wq, Wqt);
    tr_k<8, 8><<<dim3(256), blk, 0, stream>>>(Wk, Wkt);
    tr_k<8, 8><<<dim3(256), blk, 0, stream>>>(Wv, Wvt);
    tr_k<8, 8><<<dim3(256), blk, 0, stream>>>(Wo, Wot);
    tr_k<8, 8><<<dim3(256), blk, 0, stream>>>(Wenc, Wenct);
    tr_k<8, 10><<<dim3(1024), blk, 0, stream>>>(W1, W1t);   // [256][1024] -> [1024][256]
    tr_k<10, 8><<<dim3(1024), blk, 0, stream>>>(W2, W2t);   // [1024][256] -> [256][1024]

    // ---- attention (4 chunks of 8 n) ----
    for (int c = 0; c < 4; ++c) {
        qkv_k<<<dim3(2, 128, 3), blk, 0, stream>>>(
            xbf + (size_t)c * CH, Wqt, Wkt, Wvt, bq, bk, bv, qc, kcb, vT);
        qkqe_k<<<dim3(2, 1, 128), blk, 0, stream>>>(qc, kcb, Erelb, qkcb);
        softmax_k<<<dim3(4096), blk, 0, stream>>>(qkcb, attb);
        av_k<<<dim3(2, 1, 128), blk, 0, stream>>>(attb, vT, zc);
        gemm_k<256, 256, 2, float, u16><<<dim3(2, 128), blk, 0, stream>>>(
            zc, Wot, bo, x + (size_t)c * CH, h1pre + (size_t)c * CH);
    }

    // ---- BN1 ----
    bnstats_k<<<dim3(2048), blk, 0, stream>>>(h1pre, g1, be1, p1);
    bnapply_k<<<dim3(8192), blk, 0, stream>>>(h1pre, p1, h1n);

    // ---- FFN (4 chunks) ----
    for (int c = 0; c < 4; ++c) {
        gemm_k<256, 1024, 1, float, u16><<<dim3(8, 128), blk, 0, stream>>>(
            h1n + (size_t)c * CH, W1t, b1, nullptr, ff1);
        gemm_k<1024, 256, 3, u16, u16><<<dim3(2, 128), blk, 0, stream>>>(
            ff1, W2t, b2, h1n + (size_t)c * CH, h2pre + (size_t)c * CH);
    }

    // ---- BN2 + encoder ----
    bnstats_k<<<dim3(2048), blk, 0, stream>>>(h2pre, g2, be2, p2);
    bnapply_k<<<dim3(8192), blk, 0, stream>>>(h2pre, p2, h2n);
    gemm_k<256, 256, 0, float, float><<<dim3(2, 512), blk, 0, stream>>>(
        h2n, Wenct, benc, (const float*)nullptr, (float*)d_out);
}

// Round 6
// 415.778 us; speedup vs baseline: 4.5950x; 1.2752x over previous
//
#include <hip/hip_runtime.h>
#include <hip/hip_bf16.h>

using u16 = unsigned short;
typedef __attribute__((ext_vector_type(8))) short bf16x8;
typedef __attribute__((ext_vector_type(4))) float f32x4;

static constexpr float EPS_ = 1e-5f;
static constexpr float NEG_ = 0.01f;

__device__ __forceinline__ float bf2f(u16 u) { return __uint_as_float(((unsigned)u) << 16); }
__device__ __forceinline__ u16 f2bf(float f) {
    union { __hip_bfloat16 h; u16 u; } c; c.h = __float2bfloat16(f); return c.u;
}

#define MFMA16(a, b, c) __builtin_amdgcn_mfma_f32_16x16x32_bf16(a, b, c, 0, 0, 0)

// async global->LDS, 16B per lane (wave-uniform LDS base, per-lane global addr)
__device__ __forceinline__ void gload16(const u16* g, u16* l) {
    __builtin_amdgcn_global_load_lds(
        (__attribute__((address_space(1))) void*)(u16*)g,
        (__attribute__((address_space(3))) void*)l, 16, 0, 0);
}

__device__ __forceinline__ void zero_acc(f32x4 acc[4][4]) {
    #pragma unroll
    for (int i = 0; i < 4; i++)
        #pragma unroll
        for (int j = 0; j < 4; j++)
            acc[i][j] = (f32x4){0.f, 0.f, 0.f, 0.f};
}

// ---------------------------------------------------------------------------
// m97-style core: block computes 128x128 C-tile, 4 waves in 2x2, BK=64.
// A base Ag: rows m0..m0+127 of [*][lda]; B base Bg: rows n0..n0+127 of B^T.
// Single 32KB LDS buffer, 2 barriers / K-tile. k-map identical for A and B.
// ---------------------------------------------------------------------------
__device__ __forceinline__ void lds_core(
    const u16* __restrict__ Ag, int lda,
    const u16* __restrict__ Bg, int ldb, int K,
    u16* As, u16* Bs, f32x4 acc[4][4])
{
    const int tid = threadIdx.x;
    const int w = tid >> 6, lane = tid & 63;
    const int g = lane >> 4, r = lane & 15;
    const int wm = (w >> 1) * 64, wn = (w & 1) * 64;

    for (int kt = 0; kt < K; kt += 64) {
        #pragma unroll
        for (int j = 0; j < 4; j++) {
            const int ubase = (w * 4 + j) * 64;       // 16B-unit base (wave-uniform)
            const int u = ubase + lane;
            const int row = u >> 3, cb = (u & 7) * 8;
            gload16(Ag + (size_t)row * lda + kt + cb, As + ubase * 8);
            gload16(Bg + (size_t)row * ldb + kt + cb, Bs + ubase * 8);
        }
        __syncthreads();
        #pragma unroll
        for (int kk = 0; kk < 2; kk++) {
            bf16x8 af[4], bfr[4];
            #pragma unroll
            for (int f = 0; f < 4; f++) {
                af[f]  = *(const bf16x8*)(As + (wm + f * 16 + r) * 64 + kk * 32 + g * 8);
                bfr[f] = *(const bf16x8*)(Bs + (wn + f * 16 + r) * 64 + kk * 32 + g * 8);
            }
            #pragma unroll
            for (int i = 0; i < 4; i++)
                #pragma unroll
                for (int j = 0; j < 4; j++)
                    acc[i][j] = MFMA16(af[i], bfr[j], acc[i][j]);
        }
        __syncthreads();
    }
}

struct WCtx { int mb; int nb; int g; int r; };
__device__ __forceinline__ WCtx wctx(int m0, int n0) {
    const int tid = threadIdx.x;
    const int w = tid >> 6, lane = tid & 63;
    WCtx c;
    c.g = lane >> 4; c.r = lane & 15;
    c.mb = m0 + (w >> 1) * 64;
    c.nb = n0 + (w & 1) * 64;
    return c;
}

// ---------------------------------------------------------------------------
// Prep: x f32 -> bf16 (vectorized)
// ---------------------------------------------------------------------------
__global__ __launch_bounds__(256) void cvt_k(const float* __restrict__ in,
                                             u16* __restrict__ out) {
    const size_t i8 = ((size_t)blockIdx.x * 256 + threadIdx.x) * 8;
    const float4 lo = *(const float4*)(in + i8);
    const float4 hi = *(const float4*)(in + i8 + 4);
    ushort4 o0, o1;
    o0.x = f2bf(lo.x); o0.y = f2bf(lo.y); o0.z = f2bf(lo.z); o0.w = f2bf(lo.w);
    o1.x = f2bf(hi.x); o1.y = f2bf(hi.y); o1.z = f2bf(hi.z); o1.w = f2bf(hi.w);
    *(ushort4*)(out + i8) = o0;
    *(ushort4*)(out + i8 + 4) = o1;
}

// ---------------------------------------------------------------------------
// All weight prep in one kernel. grid = 5376 blocks x 256.
//  bid in [0,1280): 5 jobs of 256x256 transpose (Wq,Wk,Wv->Wqkvt; Wo; Wenc)
//  [1280,2304): W1 [256][1024] -> W1t [1024][256]
//  [2304,3328): W2 [1024][256] -> W2t [256][1024]
//  [3328,5376): Erel f32 -> bf16 copy (524288 elems)
// ---------------------------------------------------------------------------
__global__ __launch_bounds__(256) void prep_w_k(
    const float* __restrict__ Wq, const float* __restrict__ Wk,
    const float* __restrict__ Wv, const float* __restrict__ Wo,
    const float* __restrict__ Wenc, const float* __restrict__ W1,
    const float* __restrict__ W2, const float* __restrict__ Erel,
    u16* __restrict__ Wqkvt, u16* __restrict__ Wot, u16* __restrict__ Wenct,
    u16* __restrict__ W1t, u16* __restrict__ W2t, u16* __restrict__ Erelb)
{
    const int bid = blockIdx.x, tid = threadIdx.x;
    if (bid < 1280) {
        const int jb = bid >> 8;
        const int t = ((bid & 255) << 8) | tid;       // [0,65536)
        const int n = t >> 8, k = t & 255;
        const float* src = jb == 0 ? Wq : jb == 1 ? Wk : jb == 2 ? Wv
                         : jb == 3 ? Wo : Wenc;
        const u16 v = f2bf(src[(k << 8) + n]);
        if (jb < 3)      Wqkvt[jb * 65536 + t] = v;
        else if (jb == 3) Wot[t] = v;
        else              Wenct[t] = v;
    } else if (bid < 2304) {
        const int t = ((bid - 1280) << 8) | tid;      // [0,262144)
        const int n = t >> 8, k = t & 255;
        W1t[t] = f2bf(W1[(k << 10) + n]);
    } else if (bid < 3328) {
        const int t = ((bid - 2304) << 8) | tid;      // [0,262144)
        const int n = t >> 10, k = t & 1023;
        W2t[t] = f2bf(W2[(k << 8) + n]);
    } else {
        const int t = ((bid - 3328) << 8) | tid;      // [0,524288)
        Erelb[t] = f2bf(Erel[t]);
    }
}

// ---------------------------------------------------------------------------
// QKV fused: A = xbf [65536][256]; B = Wqkvt [768][256].
// n<256 -> q (n,h,l,e); 256..511 -> k (n,h,l,e); 512..767 -> vT (n,h,e,l).
// grid (6,512)
// ---------------------------------------------------------------------------
__global__ __launch_bounds__(256) void qkv_k(
    const u16* __restrict__ xbf, const u16* __restrict__ Wqkvt,
    const float* __restrict__ bq, const float* __restrict__ bk,
    const float* __restrict__ bv,
    u16* __restrict__ qo, u16* __restrict__ ko, u16* __restrict__ vo)
{
    __shared__ __align__(16) u16 As[128 * 64];
    __shared__ __align__(16) u16 Bs[128 * 64];
    const int m0 = blockIdx.y * 128, n0 = blockIdx.x * 128;
    const int which = n0 >> 8;
    const float* bias = which == 0 ? bq : (which == 1 ? bk : bv);
    u16* out = which == 0 ? qo : (which == 1 ? ko : vo);

    f32x4 acc[4][4]; zero_acc(acc);
    lds_core(xbf + (size_t)m0 * 256, 256, Wqkvt + (size_t)n0 * 256, 256, 256,
             As, Bs, acc);

    const WCtx c = wctx(m0, n0);
    #pragma unroll
    for (int fn = 0; fn < 4; fn++) {
        const int n = c.nb + fn * 16 + c.r;
        const int e = n & 255;
        const float bv4 = bias[e];
        #pragma unroll
        for (int fm = 0; fm < 4; fm++) {
            #pragma unroll
            for (int reg = 0; reg < 4; reg++) {
                const int m = c.mb + fm * 16 + c.g * 4 + reg;
                const float v = acc[fm][fn][reg] + bv4;
                const int nn = m >> 11, lh = m & 2047, l = lh >> 4, hh = lh & 15;
                const size_t oidx = (which == 2)
                    ? ((size_t)(nn * 16 + hh) * 256 + e) * 128 + l
                    : ((size_t)(nn * 16 + hh) * 128 + l) * 256 + e;
                out[oidx] = f2bf(v);
            }
        }
    }
}

// ---------------------------------------------------------------------------
// [qk/16 | QE] batched over all b in [0,512). grid (2,1,512)
// ---------------------------------------------------------------------------
__global__ __launch_bounds__(256) void qkqe_k(
    const u16* __restrict__ q, const u16* __restrict__ kc,
    const u16* __restrict__ erel, u16* __restrict__ out)
{
    __shared__ __align__(16) u16 As[128 * 64];
    __shared__ __align__(16) u16 Bs[128 * 64];
    const int b = blockIdx.z, h = b & 15;
    const int n0 = blockIdx.x * 128;
    const u16* Ag = q + (size_t)b * 128 * 256;
    const u16* Bg = (n0 == 0) ? (kc + (size_t)b * 128 * 256)
                              : (erel + (size_t)h * 128 * 256);

    f32x4 acc[4][4]; zero_acc(acc);
    lds_core(Ag, 256, Bg, 256, 256, As, Bs, acc);

    const WCtx c = wctx(0, n0);
    const float scale = (n0 == 0) ? 0.0625f : 1.0f;
    #pragma unroll
    for (int fm = 0; fm < 4; fm++)
        #pragma unroll
        for (int fn = 0; fn < 4; fn++)
            #pragma unroll
            for (int reg = 0; reg < 4; reg++) {
                const int m = c.mb + fm * 16 + c.g * 4 + reg;
                const int n = c.nb + fn * 16 + c.r;
                out[((size_t)b * 128 + m) * 256 + n] = f2bf(acc[fm][fn][reg] * scale);
            }
}

// ---------------------------------------------------------------------------
// softmax + skewed-S add. S[i,c] = QE[i][127-i+c] for c<=i.
// ---------------------------------------------------------------------------
__global__ __launch_bounds__(256) void softmax_k(
    const u16* __restrict__ qk, u16* __restrict__ att)
{
    const int r = blockIdx.x * 4 + (threadIdx.x >> 6);
    const int lane = threadIdx.x & 63;
    const int i = r & 127;
    const u16* row = qk + (size_t)r * 256;
    const float x0 = bf2f(row[lane]), x1 = bf2f(row[lane + 64]);
    float mx = fmaxf(x0, x1);
    #pragma unroll
    for (int o = 32; o; o >>= 1) mx = fmaxf(mx, __shfl_xor(mx, o));
    const float e0 = __expf(x0 - mx), e1 = __expf(x1 - mx);
    float s = e0 + e1;
    #pragma unroll
    for (int o = 32; o; o >>= 1) s += __shfl_xor(s, o);
    const float rinv = 1.0f / s;
    const float s0 = (lane <= i) ? bf2f(row[128 + 127 - i + lane]) : 0.f;
    const float s1 = (lane + 64 <= i) ? bf2f(row[128 + 127 - i + lane + 64]) : 0.f;
    att[(size_t)r * 128 + lane] = f2bf(e0 * rinv + s0);
    att[(size_t)r * 128 + lane + 64] = f2bf(e1 * rinv + s1);
}

// ---------------------------------------------------------------------------
// z = att[b] (128x128) @ v[b] (via vT [e][l]); out zc in m-order.
// grid (2,1,512)
// ---------------------------------------------------------------------------
__global__ __launch_bounds__(256) void av_k(
    const u16* __restrict__ att, const u16* __restrict__ vT,
    u16* __restrict__ zc)
{
    __shared__ __align__(16) u16 As[128 * 64];
    __shared__ __align__(16) u16 Bs[128 * 64];
    const int b = blockIdx.z;
    const int n0 = blockIdx.x * 128;
    const u16* Ag = att + (size_t)b * 128 * 128;
    const u16* Bg = vT + (size_t)b * 256 * 128 + (size_t)n0 * 128;

    f32x4 acc[4][4]; zero_acc(acc);
    lds_core(Ag, 128, Bg, 128, 128, As, Bs, acc);

    const WCtx c = wctx(0, n0);
    const int nn = b >> 4, hh = b & 15;
    #pragma unroll
    for (int fm = 0; fm < 4; fm++)
        #pragma unroll
        for (int fn = 0; fn < 4; fn++)
            #pragma unroll
            for (int reg = 0; reg < 4; reg++) {
                const int i = c.mb + fm * 16 + c.g * 4 + reg;   // query row
                const int n = c.nb + fn * 16 + c.r;             // e
                zc[((size_t)(nn * 2048 + i * 16 + hh)) * 256 + n] =
                    f2bf(acc[fm][fn][reg]);
            }
}

// ---------------------------------------------------------------------------
// Generic GEMM: out[m][Nn] = A[m][K] @ Wt^T + bias (+epilogue)
// EPI: 0 plain; 1 leaky; 3 +res bf16.  TO: u16 or float. grid (Nn/128, M/128)
// ---------------------------------------------------------------------------
template<int K, int Nn, int EPI, typename TO>
__global__ __launch_bounds__(256) void gemm_k(
    const u16* __restrict__ A, const u16* __restrict__ Wt,
    const float* __restrict__ bias, const u16* __restrict__ res,
    TO* __restrict__ out)
{
    __shared__ __align__(16) u16 As[128 * 64];
    __shared__ __align__(16) u16 Bs[128 * 64];
    const int m0 = blockIdx.y * 128, n0 = blockIdx.x * 128;

    f32x4 acc[4][4]; zero_acc(acc);
    lds_core(A + (size_t)m0 * K, K, Wt + (size_t)n0 * K, K, K, As, Bs, acc);

    const WCtx c = wctx(m0, n0);
    #pragma unroll
    for (int fn = 0; fn < 4; fn++) {
        const int n = c.nb + fn * 16 + c.r;
        const float bv4 = bias[n];
        #pragma unroll
        for (int fm = 0; fm < 4; fm++) {
            #pragma unroll
            for (int reg = 0; reg < 4; reg++) {
                const int m = c.mb + fm * 16 + c.g * 4 + reg;
                float v = acc[fm][fn][reg] + bv4;
                if constexpr (EPI == 3)
                    v += bf2f(res[(size_t)m * Nn + n]);
                if constexpr (EPI == 1)
                    v = v >= 0.f ? v : NEG_ * v;
                if constexpr (sizeof(TO) == 2) out[(size_t)m * Nn + n] = f2bf(v);
                else                           out[(size_t)m * Nn + n] = v;
            }
        }
    }
}

// ---------------------------------------------------------------------------
// batchnorm stats over (n, e) per channel c (bf16 input, 65536 rows)
// ---------------------------------------------------------------------------
__global__ __launch_bounds__(256) void bnstats_k(
    const u16* __restrict__ x, const float* __restrict__ g,
    const float* __restrict__ be, float2* __restrict__ params)
{
    const int c = blockIdx.x, tid = threadIdx.x;
    float s = 0.f, s2 = 0.f;
    #pragma unroll 4
    for (int n = 0; n < 32; n++) {
        const float v = bf2f(x[((size_t)n * 2048 + c) * 256 + tid]);
        s += v; s2 += v * v;
    }
    #pragma unroll
    for (int o = 32; o; o >>= 1) { s += __shfl_xor(s, o); s2 += __shfl_xor(s2, o); }
    __shared__ float rs[4], rs2[4];
    const int w = tid >> 6;
    if ((tid & 63) == 0) { rs[w] = s; rs2[w] = s2; }
    __syncthreads();
    if (tid == 0) {
        s  = rs[0] + rs[1] + rs[2] + rs[3];
        s2 = rs2[0] + rs2[1] + rs2[2] + rs2[3];
        const float mean = s / 8192.f;
        const float var = s2 / 8192.f - mean * mean;
        const float a = g[c] * rsqrtf(var + EPS_);
        params[c] = make_float2(a, be[c] - mean * a);
    }
}

__global__ __launch_bounds__(256) void bnapply_k(
    const u16* __restrict__ in, const float2* __restrict__ p,
    u16* __restrict__ out)
{
    const size_t idx = (size_t)blockIdx.x * 256 + threadIdx.x;  // ushort8 unit
    const int c = (int)((idx >> 5) & 2047);
    const float2 pp = p[c];
    const ushort4 v0 = ((const ushort4*)(in + idx * 8))[0];
    const ushort4 v1 = ((const ushort4*)(in + idx * 8))[1];
    ushort4 o0, o1;
    o0.x = f2bf(bf2f(v0.x) * pp.x + pp.y);
    o0.y = f2bf(bf2f(v0.y) * pp.x + pp.y);
    o0.z = f2bf(bf2f(v0.z) * pp.x + pp.y);
    o0.w = f2bf(bf2f(v0.w) * pp.x + pp.y);
    o1.x = f2bf(bf2f(v1.x) * pp.x + pp.y);
    o1.y = f2bf(bf2f(v1.y) * pp.x + pp.y);
    o1.z = f2bf(bf2f(v1.z) * pp.x + pp.y);
    o1.w = f2bf(bf2f(v1.w) * pp.x + pp.y);
    ((ushort4*)(out + idx * 8))[0] = o0;
    ((ushort4*)(out + idx * 8))[1] = o1;
}

// ---------------------------------------------------------------------------
extern "C" void kernel_launch(void* const* d_in, const int* in_sizes, int n_in,
                              void* d_out, int out_size, void* d_ws, size_t ws_size,
                              hipStream_t stream)
{
    const float* x    = (const float*)d_in[0];
    const float* Wq   = (const float*)d_in[1];
    const float* bq   = (const float*)d_in[2];
    const float* Wk   = (const float*)d_in[3];
    const float* bk   = (const float*)d_in[4];
    const float* Wv   = (const float*)d_in[5];
    const float* bv   = (const float*)d_in[6];
    const float* Erel = (const float*)d_in[7];
    const float* Wo   = (const float*)d_in[8];
    const float* bo   = (const float*)d_in[9];
    const float* g1   = (const float*)d_in[10];
    const float* be1  = (const float*)d_in[11];
    const float* g2   = (const float*)d_in[12];
    const float* be2  = (const float*)d_in[13];
    const float* W1   = (const float*)d_in[14];
    const float* b1   = (const float*)d_in[15];
    const float* W2   = (const float*)d_in[16];
    const float* b2   = (const float*)d_in[17];
    const float* Wenc = (const float*)d_in[18];
    const float* benc = (const float*)d_in[19];

    char* ws = (char*)d_ws;
    const size_t MB = 1ull << 20;
    const size_t KB = 1024;
    // unchunked layout (peak ~244 MB of the 256 MiB ws)
    u16* xbf   = (u16*)(ws + 0 * MB);     // 32 MB; reused as h2n after Wo
    u16* h2n   = (u16*)(ws + 0 * MB);
    u16* qb    = (u16*)(ws + 32 * MB);    // 32 MB; reused as h1n after attn
    u16* h1n   = (u16*)(ws + 32 * MB);
    u16* kb    = (u16*)(ws + 64 * MB);    // 32 MB -- reused as ff1 part
    u16* vT    = (u16*)(ws + 96 * MB);    // 32 MB -- reused as ff1 part
    u16* qkb   = (u16*)(ws + 128 * MB);   // 32 MB -- reused as ff1 part
    u16* attb  = (u16*)(ws + 160 * MB);   // 16 MB -- reused as ff1 part
    u16* ff1   = (u16*)(ws + 64 * MB);    // 128 MB spanning kb..attb
    u16* zc    = (u16*)(ws + 176 * MB);   // 32 MB
    u16* h1pre = (u16*)(ws + 208 * MB);   // 32 MB; reused as h2pre after BN1 apply
    u16* h2pre = (u16*)(ws + 208 * MB);
    // weights
    u16* Wqkvt = (u16*)(ws + 240 * MB);                    // 384 KB
    u16* Wot   = (u16*)(ws + 240 * MB + 512 * KB);         // 128 KB
    u16* Wenct = (u16*)(ws + 240 * MB + 640 * KB);         // 128 KB
    u16* W1t   = (u16*)(ws + 240 * MB + 768 * KB);         // 512 KB
    u16* W2t   = (u16*)(ws + 240 * MB + 1280 * KB);        // 512 KB
    u16* Erelb = (u16*)(ws + 240 * MB + 1792 * KB);        // 1 MB
    float2* p1 = (float2*)(ws + 243 * MB);
    float2* p2 = (float2*)(ws + 243 * MB + 16 * KB);

    const dim3 blk(256);

    // ---- prep ----
    cvt_k<<<dim3(8192), blk, 0, stream>>>(x, xbf);
    prep_w_k<<<dim3(5376), blk, 0, stream>>>(Wq, Wk, Wv, Wo, Wenc, W1, W2, Erel,
                                             Wqkvt, Wot, Wenct, W1t, W2t, Erelb);

    // ---- attention (unchunked) ----
    qkv_k<<<dim3(6, 512), blk, 0, stream>>>(xbf, Wqkvt, bq, bk, bv, qb, kb, vT);
    qkqe_k<<<dim3(2, 1, 512), blk, 0, stream>>>(qb, kb, Erelb, qkb);
    softmax_k<<<dim3(16384), blk, 0, stream>>>(qkb, attb);
    av_k<<<dim3(2, 1, 512), blk, 0, stream>>>(attb, vT, zc);
    gemm_k<256, 256, 3, u16><<<dim3(2, 512), blk, 0, stream>>>(
        zc, Wot, bo, xbf, h1pre);

    // ---- BN1 ----
    bnstats_k<<<dim3(2048), blk, 0, stream>>>(h1pre, g1, be1, p1);
    bnapply_k<<<dim3(8192), blk, 0, stream>>>(h1pre, p1, h1n);

    // ---- FFN (unchunked) ----
    gemm_k<256, 1024, 1, u16><<<dim3(8, 512), blk, 0, stream>>>(
        h1n, W1t, b1, nullptr, ff1);
    gemm_k<1024, 256, 3, u16><<<dim3(2, 512), blk, 0, stream>>>(
        ff1, W2t, b2, h1n, h2pre);

    // ---- BN2 + encoder ----
    bnstats_k<<<dim3(2048), blk, 0, stream>>>(h2pre, g2, be2, p2);
    bnapply_k<<<dim3(8192), blk, 0, stream>>>(h2pre, p2, h2n);
    gemm_k<256, 256, 0, float><<<dim3(2, 512), blk, 0, stream>>>(
        h2n, Wenct, benc, nullptr, (float*)d_out);
}

// Round 7
// 328.340 us; speedup vs baseline: 5.8186x; 1.2663x over previous
//
#include <hip/hip_runtime.h>
#include <hip/hip_bf16.h>

using u16 = unsigned short;
typedef __attribute__((ext_vector_type(8))) short bf16x8;
typedef __attribute__((ext_vector_type(4))) float f32x4;

static constexpr float EPS_ = 1e-5f;
static constexpr float NEG_ = 0.01f;

__device__ __forceinline__ float bf2f(u16 u) { return __uint_as_float(((unsigned)u) << 16); }
__device__ __forceinline__ u16 f2bf(float f) {
    union { __hip_bfloat16 h; u16 u; } c; c.h = __float2bfloat16(f); return c.u;
}

#define MFMA16(a, b, c) __builtin_amdgcn_mfma_f32_16x16x32_bf16(a, b, c, 0, 0, 0)

// async global->LDS, 16B per lane (wave-uniform LDS base, per-lane global addr)
__device__ __forceinline__ void gload16(const u16* g, u16* l) {
    __builtin_amdgcn_global_load_lds(
        (__attribute__((address_space(1))) void*)(u16*)g,
        (__attribute__((address_space(3))) void*)l, 16, 0, 0);
}

__device__ __forceinline__ void zero_acc(f32x4 acc[4][4]) {
    #pragma unroll
    for (int i = 0; i < 4; i++)
        #pragma unroll
        for (int j = 0; j < 4; j++)
            acc[i][j] = (f32x4){0.f, 0.f, 0.f, 0.f};
}

// XCD-aware swizzle: HW block b (round-robin over 8 XCDs) -> logical id such
// that each XCD owns a contiguous logical chunk. Requires nwg % 8 == 0.
__device__ __forceinline__ int xswz(int nwg) {
    const int b = blockIdx.x;
    return (b & 7) * (nwg >> 3) + (b >> 3);
}

// ---------------------------------------------------------------------------
// m97-style core: block computes 128x128 C-tile, 4 waves in 2x2, BK=64.
// ---------------------------------------------------------------------------
__device__ __forceinline__ void lds_core(
    const u16* __restrict__ Ag, int lda,
    const u16* __restrict__ Bg, int ldb, int K,
    u16* As, u16* Bs, f32x4 acc[4][4])
{
    const int tid = threadIdx.x;
    const int w = tid >> 6, lane = tid & 63;
    const int g = lane >> 4, r = lane & 15;
    const int wm = (w >> 1) * 64, wn = (w & 1) * 64;

    for (int kt = 0; kt < K; kt += 64) {
        #pragma unroll
        for (int j = 0; j < 4; j++) {
            const int ubase = (w * 4 + j) * 64;
            const int u = ubase + lane;
            const int row = u >> 3, cb = (u & 7) * 8;
            gload16(Ag + (size_t)row * lda + kt + cb, As + ubase * 8);
            gload16(Bg + (size_t)row * ldb + kt + cb, Bs + ubase * 8);
        }
        __syncthreads();
        #pragma unroll
        for (int kk = 0; kk < 2; kk++) {
            bf16x8 af[4], bfr[4];
            #pragma unroll
            for (int f = 0; f < 4; f++) {
                af[f]  = *(const bf16x8*)(As + (wm + f * 16 + r) * 64 + kk * 32 + g * 8);
                bfr[f] = *(const bf16x8*)(Bs + (wn + f * 16 + r) * 64 + kk * 32 + g * 8);
            }
            #pragma unroll
            for (int i = 0; i < 4; i++)
                #pragma unroll
                for (int j = 0; j < 4; j++)
                    acc[i][j] = MFMA16(af[i], bfr[j], acc[i][j]);
        }
        __syncthreads();
    }
}

// ---------------------------------------------------------------------------
// Staged coalesced bf16 epilogue. Stage C (128x128, stride 136) in LDS,
// then 8 x 16B chunks per thread, full-line stores.
// EPI: 0 plain, 1 leaky, 3 +bf16 residual (added in store pass).
// VTRANS: stage at [col][ (row&15)*8 + (row>>4) ] for the V-transpose layout.
// outp(row, cc) / resp(row, cc) -> u16* of the 16B chunk.
// ---------------------------------------------------------------------------
template<int EPI, bool VTRANS, typename OutF, typename ResF>
__device__ __forceinline__ void epi_store(
    u16* Cs, f32x4 (&acc)[4][4], const float* biasBase, float scale,
    OutF outp, ResF resp)
{
    const int tid = threadIdx.x;
    const int w = tid >> 6, lane = tid & 63;
    const int g = lane >> 4, r = lane & 15;
    const int mb = (w >> 1) * 64, nb = (w & 1) * 64;

    #pragma unroll
    for (int fn = 0; fn < 4; fn++) {
        const int col = nb + fn * 16 + r;
        const float bv = biasBase ? biasBase[col] : 0.f;
        #pragma unroll
        for (int fm = 0; fm < 4; fm++) {
            #pragma unroll
            for (int reg = 0; reg < 4; reg++) {
                const int row = mb + fm * 16 + g * 4 + reg;
                float v = acc[fm][fn][reg] * scale + bv;
                if (EPI == 1) v = v >= 0.f ? v : NEG_ * v;
                int R, C;
                if (VTRANS) { R = col; C = ((row & 15) << 3) | (row >> 4); }
                else        { R = row; C = col; }
                Cs[R * 136 + C] = f2bf(v);
            }
        }
    }
    __syncthreads();
    #pragma unroll
    for (int p = 0; p < 8; p++) {
        const int ck = p * 256 + tid;
        const int row = ck >> 4, cc = ck & 15;
        bf16x8 v = *(const bf16x8*)(Cs + row * 136 + cc * 8);
        if constexpr (EPI == 3) {
            const bf16x8 rv = *(const bf16x8*)resp(row, cc);
            #pragma unroll
            for (int j = 0; j < 8; j++)
                v[j] = (short)f2bf(bf2f((u16)v[j]) + bf2f((u16)rv[j]));
        }
        *(bf16x8*)outp(row, cc) = v;
    }
}

// ---------------------------------------------------------------------------
// Prep kernels
// ---------------------------------------------------------------------------
__global__ __launch_bounds__(256) void cvt_k(const float* __restrict__ in,
                                             u16* __restrict__ out) {
    const size_t i8 = ((size_t)blockIdx.x * 256 + threadIdx.x) * 8;
    const float4 lo = *(const float4*)(in + i8);
    const float4 hi = *(const float4*)(in + i8 + 4);
    ushort4 o0, o1;
    o0.x = f2bf(lo.x); o0.y = f2bf(lo.y); o0.z = f2bf(lo.z); o0.w = f2bf(lo.w);
    o1.x = f2bf(hi.x); o1.y = f2bf(hi.y); o1.z = f2bf(hi.z); o1.w = f2bf(hi.w);
    *(ushort4*)(out + i8) = o0;
    *(ushort4*)(out + i8 + 4) = o1;
}

__global__ __launch_bounds__(256) void prep_w_k(
    const float* __restrict__ Wq, const float* __restrict__ Wk,
    const float* __restrict__ Wv, const float* __restrict__ Wo,
    const float* __restrict__ Wenc, const float* __restrict__ W1,
    const float* __restrict__ W2, const float* __restrict__ Erel,
    u16* __restrict__ Wqkvt, u16* __restrict__ Wot, u16* __restrict__ Wenct,
    u16* __restrict__ W1t, u16* __restrict__ W2t, u16* __restrict__ Erelb)
{
    const int bid = blockIdx.x, tid = threadIdx.x;
    if (bid < 1280) {
        const int jb = bid >> 8;
        const int t = ((bid & 255) << 8) | tid;
        const int n = t >> 8, k = t & 255;
        const float* src = jb == 0 ? Wq : jb == 1 ? Wk : jb == 2 ? Wv
                         : jb == 3 ? Wo : Wenc;
        const u16 v = f2bf(src[(k << 8) + n]);
        if (jb < 3)       Wqkvt[jb * 65536 + t] = v;
        else if (jb == 3) Wot[t] = v;
        else              Wenct[t] = v;
    } else if (bid < 2304) {
        const int t = ((bid - 1280) << 8) | tid;
        const int n = t >> 8, k = t & 255;
        W1t[t] = f2bf(W1[(k << 10) + n]);
    } else if (bid < 3328) {
        const int t = ((bid - 2304) << 8) | tid;
        const int n = t >> 10, k = t & 1023;
        W2t[t] = f2bf(W2[(k << 8) + n]);
    } else {
        const int t = ((bid - 3328) << 8) | tid;
        Erelb[t] = f2bf(Erel[t]);
    }
}

// ---------------------------------------------------------------------------
// QKV fused: A = xbf [65536][256]; B = Wqkvt [768][256]. grid 3072 (1D).
// n<256 -> q (n,h,l,e); 256..511 -> k (n,h,l,e); 512..767 -> vT (n,h,e,l).
// ---------------------------------------------------------------------------
__global__ __launch_bounds__(256) void qkv_k(
    const u16* __restrict__ xbf, const u16* __restrict__ Wqkvt,
    const float* __restrict__ bq, const float* __restrict__ bk,
    const float* __restrict__ bv,
    u16* __restrict__ qo, u16* __restrict__ ko, u16* __restrict__ vo)
{
    __shared__ __align__(16) u16 SH[17408];
    u16* As = SH; u16* Bs = SH + 8192;
    const int f = xswz(3072);
    const int nblk = f % 6, mblk = f / 6;
    const int m0 = mblk * 128, n0 = nblk * 128;
    const int which = n0 >> 8;
    const float* bias = which == 0 ? bq : (which == 1 ? bk : bv);
    const int e0 = n0 & 255;

    f32x4 acc[4][4]; zero_acc(acc);
    lds_core(xbf + (size_t)m0 * 256, 256, Wqkvt + (size_t)n0 * 256, 256, 256,
             As, Bs, acc);

    const int nn = m0 >> 11, l0 = (m0 & 2047) >> 4;
    auto dummy = [&](int, int) -> const u16* { return nullptr; };
    if (which == 2) {
        epi_store<0, true>(SH, acc, bias + e0, 1.f,
            [&](int row, int cc) -> u16* {
                return vo + ((size_t)(nn * 16 + cc) * 256 + e0 + row) * 128 + l0;
            }, dummy);
    } else {
        u16* out = which == 0 ? qo : ko;
        epi_store<0, false>(SH, acc, bias + e0, 1.f,
            [&](int row, int cc) -> u16* {
                const int m = m0 + row;
                const int l = (m & 2047) >> 4, hh = m & 15;
                return out + ((size_t)(nn * 16 + hh) * 128 + l) * 256 + e0 + cc * 8;
            }, dummy);
    }
}

// ---------------------------------------------------------------------------
// [qk/16 | QE] batched. grid 1024 (1D): b = f>>1, n0 = (f&1)*128.
// ---------------------------------------------------------------------------
__global__ __launch_bounds__(256) void qkqe_k(
    const u16* __restrict__ q, const u16* __restrict__ kc,
    const u16* __restrict__ erel, u16* __restrict__ out)
{
    __shared__ __align__(16) u16 SH[17408];
    u16* As = SH; u16* Bs = SH + 8192;
    const int f = xswz(1024);
    const int b = f >> 1, h = b & 15;
    const int n0 = (f & 1) * 128;
    const u16* Ag = q + (size_t)b * 128 * 256;
    const u16* Bg = (n0 == 0) ? (kc + (size_t)b * 128 * 256)
                              : (erel + (size_t)h * 128 * 256);

    f32x4 acc[4][4]; zero_acc(acc);
    lds_core(Ag, 256, Bg, 256, 256, As, Bs, acc);

    const float scale = (n0 == 0) ? 0.0625f : 1.0f;
    auto dummy = [&](int, int) -> const u16* { return nullptr; };
    epi_store<0, false>(SH, acc, nullptr, scale,
        [&](int row, int cc) -> u16* {
            return out + ((size_t)b * 128 + row) * 256 + n0 + cc * 8;
        }, dummy);
}

// ---------------------------------------------------------------------------
// softmax + skewed-S add. S[i,c] = QE[i][127-i+c] for c<=i.
// ---------------------------------------------------------------------------
__global__ __launch_bounds__(256) void softmax_k(
    const u16* __restrict__ qk, u16* __restrict__ att)
{
    const int r = blockIdx.x * 4 + (threadIdx.x >> 6);
    const int lane = threadIdx.x & 63;
    const int i = r & 127;
    const u16* row = qk + (size_t)r * 256;
    const float x0 = bf2f(row[lane]), x1 = bf2f(row[lane + 64]);
    float mx = fmaxf(x0, x1);
    #pragma unroll
    for (int o = 32; o; o >>= 1) mx = fmaxf(mx, __shfl_xor(mx, o));
    const float e0 = __expf(x0 - mx), e1 = __expf(x1 - mx);
    float s = e0 + e1;
    #pragma unroll
    for (int o = 32; o; o >>= 1) s += __shfl_xor(s, o);
    const float rinv = 1.0f / s;
    const float s0 = (lane <= i) ? bf2f(row[128 + 127 - i + lane]) : 0.f;
    const float s1 = (lane + 64 <= i) ? bf2f(row[128 + 127 - i + lane + 64]) : 0.f;
    att[(size_t)r * 128 + lane] = f2bf(e0 * rinv + s0);
    att[(size_t)r * 128 + lane + 64] = f2bf(e1 * rinv + s1);
}

// ---------------------------------------------------------------------------
// z = att[b] (128x128) @ v[b] (via vT [e][l]); out zc in m-order. grid 1024.
// ---------------------------------------------------------------------------
__global__ __launch_bounds__(256) void av_k(
    const u16* __restrict__ att, const u16* __restrict__ vT,
    u16* __restrict__ zc)
{
    __shared__ __align__(16) u16 SH[17408];
    u16* As = SH; u16* Bs = SH + 8192;
    const int f = xswz(1024);
    const int b = f >> 1;
    const int n0 = (f & 1) * 128;
    const u16* Ag = att + (size_t)b * 128 * 128;
    const u16* Bg = vT + (size_t)b * 256 * 128 + (size_t)n0 * 128;

    f32x4 acc[4][4]; zero_acc(acc);
    lds_core(Ag, 128, Bg, 128, 128, As, Bs, acc);

    const int nn = b >> 4, hh = b & 15;
    auto dummy = [&](int, int) -> const u16* { return nullptr; };
    epi_store<0, false>(SH, acc, nullptr, 1.f,
        [&](int row, int cc) -> u16* {
            return zc + ((size_t)(nn * 2048 + row * 16 + hh)) * 256 + n0 + cc * 8;
        }, dummy);
}

// ---------------------------------------------------------------------------
// Generic GEMM: out[m][Nn] = A[m][K] @ Wt^T + bias (+epilogue)
// EPI: 0 plain; 1 leaky; 3 +res bf16.  TO: u16 (staged) or float (scalar).
// grid 1D = 512 * (Nn/128)
// ---------------------------------------------------------------------------
template<int K, int Nn, int EPI, typename TO>
__global__ __launch_bounds__(256) void gemm_k(
    const u16* __restrict__ A, const u16* __restrict__ Wt,
    const float* __restrict__ bias, const u16* __restrict__ res,
    TO* __restrict__ out)
{
    __shared__ __align__(16) u16 SH[17408];
    u16* As = SH; u16* Bs = SH + 8192;
    constexpr int NB = Nn / 128;
    const int f = xswz(512 * NB);
    const int m0 = (f / NB) * 128, n0 = (f % NB) * 128;

    f32x4 acc[4][4]; zero_acc(acc);
    lds_core(A + (size_t)m0 * K, K, Wt + (size_t)n0 * K, K, K, As, Bs, acc);

    if constexpr (sizeof(TO) == 2) {
        epi_store<EPI, false>(SH, acc, bias + n0, 1.f,
            [&](int row, int cc) -> u16* {
                return ((u16*)out) + (size_t)(m0 + row) * Nn + n0 + cc * 8;
            },
            [&](int row, int cc) -> const u16* {
                return res + (size_t)(m0 + row) * Nn + n0 + cc * 8;
            });
    } else {
        // f32 output: scalar stores already hit full 64B lines
        const int tid = threadIdx.x;
        const int w = tid >> 6, lane = tid & 63;
        const int g = lane >> 4, r = lane & 15;
        const int mb = m0 + (w >> 1) * 64, nb = n0 + (w & 1) * 64;
        #pragma unroll
        for (int fn = 0; fn < 4; fn++) {
            const int n = nb + fn * 16 + r;
            const float bv4 = bias[n];
            #pragma unroll
            for (int fm = 0; fm < 4; fm++) {
                #pragma unroll
                for (int reg = 0; reg < 4; reg++) {
                    const int m = mb + fm * 16 + g * 4 + reg;
                    ((float*)out)[(size_t)m * Nn + n] = acc[fm][fn][reg] + bv4;
                }
            }
        }
    }
}

// ---------------------------------------------------------------------------
// batchnorm stats over (n, e) per channel c (bf16 input, 65536 rows)
// ---------------------------------------------------------------------------
__global__ __launch_bounds__(256) void bnstats_k(
    const u16* __restrict__ x, const float* __restrict__ g,
    const float* __restrict__ be, float2* __restrict__ params)
{
    const int c = blockIdx.x, tid = threadIdx.x;
    float s = 0.f, s2 = 0.f;
    #pragma unroll 4
    for (int n = 0; n < 32; n++) {
        const float v = bf2f(x[((size_t)n * 2048 + c) * 256 + tid]);
        s += v; s2 += v * v;
    }
    #pragma unroll
    for (int o = 32; o; o >>= 1) { s += __shfl_xor(s, o); s2 += __shfl_xor(s2, o); }
    __shared__ float rs[4], rs2[4];
    const int w = tid >> 6;
    if ((tid & 63) == 0) { rs[w] = s; rs2[w] = s2; }
    __syncthreads();
    if (tid == 0) {
        s  = rs[0] + rs[1] + rs[2] + rs[3];
        s2 = rs2[0] + rs2[1] + rs2[2] + rs2[3];
        const float mean = s / 8192.f;
        const float var = s2 / 8192.f - mean * mean;
        const float a = g[c] * rsqrtf(var + EPS_);
        params[c] = make_float2(a, be[c] - mean * a);
    }
}

__global__ __launch_bounds__(256) void bnapply_k(
    const u16* __restrict__ in, const float2* __restrict__ p,
    u16* __restrict__ out)
{
    const size_t idx = (size_t)blockIdx.x * 256 + threadIdx.x;
    const int c = (int)((idx >> 5) & 2047);
    const float2 pp = p[c];
    const ushort4 v0 = ((const ushort4*)(in + idx * 8))[0];
    const ushort4 v1 = ((const ushort4*)(in + idx * 8))[1];
    ushort4 o0, o1;
    o0.x = f2bf(bf2f(v0.x) * pp.x + pp.y);
    o0.y = f2bf(bf2f(v0.y) * pp.x + pp.y);
    o0.z = f2bf(bf2f(v0.z) * pp.x + pp.y);
    o0.w = f2bf(bf2f(v0.w) * pp.x + pp.y);
    o1.x = f2bf(bf2f(v1.x) * pp.x + pp.y);
    o1.y = f2bf(bf2f(v1.y) * pp.x + pp.y);
    o1.z = f2bf(bf2f(v1.z) * pp.x + pp.y);
    o1.w = f2bf(bf2f(v1.w) * pp.x + pp.y);
    ((ushort4*)(out + idx * 8))[0] = o0;
    ((ushort4*)(out + idx * 8))[1] = o1;
}

// ---------------------------------------------------------------------------
extern "C" void kernel_launch(void* const* d_in, const int* in_sizes, int n_in,
                              void* d_out, int out_size, void* d_ws, size_t ws_size,
                              hipStream_t stream)
{
    const float* x    = (const float*)d_in[0];
    const float* Wq   = (const float*)d_in[1];
    const float* bq   = (const float*)d_in[2];
    const float* Wk   = (const float*)d_in[3];
    const float* bk   = (const float*)d_in[4];
    const float* Wv   = (const float*)d_in[5];
    const float* bv   = (const float*)d_in[6];
    const float* Erel = (const float*)d_in[7];
    const float* Wo   = (const float*)d_in[8];
    const float* bo   = (const float*)d_in[9];
    const float* g1   = (const float*)d_in[10];
    const float* be1  = (const float*)d_in[11];
    const float* g2   = (const float*)d_in[12];
    const float* be2  = (const float*)d_in[13];
    const float* W1   = (const float*)d_in[14];
    const float* b1   = (const float*)d_in[15];
    const float* W2   = (const float*)d_in[16];
    const float* b2   = (const float*)d_in[17];
    const float* Wenc = (const float*)d_in[18];
    const float* benc = (const float*)d_in[19];

    char* ws = (char*)d_ws;
    const size_t MB = 1ull << 20;
    const size_t KB = 1024;
    u16* xbf   = (u16*)(ws + 0 * MB);     // 32 MB; reused as h2n after Wo
    u16* h2n   = (u16*)(ws + 0 * MB);
    u16* qb    = (u16*)(ws + 32 * MB);    // 32 MB; reused as h1n after attn
    u16* h1n   = (u16*)(ws + 32 * MB);
    u16* kb    = (u16*)(ws + 64 * MB);    // 32 MB (ff1 reuses 64..192)
    u16* vT    = (u16*)(ws + 96 * MB);    // 32 MB
    u16* qkb   = (u16*)(ws + 128 * MB);   // 32 MB
    u16* attb  = (u16*)(ws + 160 * MB);   // 16 MB
    u16* ff1   = (u16*)(ws + 64 * MB);    // 128 MB spanning kb..attb
    u16* zc    = (u16*)(ws + 176 * MB);   // 32 MB
    u16* h1pre = (u16*)(ws + 208 * MB);   // 32 MB; reused as h2pre
    u16* h2pre = (u16*)(ws + 208 * MB);
    u16* Wqkvt = (u16*)(ws + 240 * MB);
    u16* Wot   = (u16*)(ws + 240 * MB + 512 * KB);
    u16* Wenct = (u16*)(ws + 240 * MB + 640 * KB);
    u16* W1t   = (u16*)(ws + 240 * MB + 768 * KB);
    u16* W2t   = (u16*)(ws + 240 * MB + 1280 * KB);
    u16* Erelb = (u16*)(ws + 240 * MB + 1792 * KB);
    float2* p1 = (float2*)(ws + 243 * MB);
    float2* p2 = (float2*)(ws + 243 * MB + 16 * KB);

    const dim3 blk(256);

    // ---- prep ----
    cvt_k<<<dim3(8192), blk, 0, stream>>>(x, xbf);
    prep_w_k<<<dim3(5376), blk, 0, stream>>>(Wq, Wk, Wv, Wo, Wenc, W1, W2, Erel,
                                             Wqkvt, Wot, Wenct, W1t, W2t, Erelb);

    // ---- attention ----
    qkv_k<<<dim3(3072), blk, 0, stream>>>(xbf, Wqkvt, bq, bk, bv, qb, kb, vT);
    qkqe_k<<<dim3(1024), blk, 0, stream>>>(qb, kb, Erelb, qkb);
    softmax_k<<<dim3(16384), blk, 0, stream>>>(qkb, attb);
    av_k<<<dim3(1024), blk, 0, stream>>>(attb, vT, zc);
    gemm_k<256, 256, 3, u16><<<dim3(1024), blk, 0, stream>>>(
        zc, Wot, bo, xbf, h1pre);

    // ---- BN1 ----
    bnstats_k<<<dim3(2048), blk, 0, stream>>>(h1pre, g1, be1, p1);
    bnapply_k<<<dim3(8192), blk, 0, stream>>>(h1pre, p1, h1n);

    // ---- FFN ----
    gemm_k<256, 1024, 1, u16><<<dim3(4096), blk, 0, stream>>>(
        h1n, W1t, b1, nullptr, ff1);
    gemm_k<1024, 256, 3, u16><<<dim3(1024), blk, 0, stream>>>(
        ff1, W2t, b2, h1n, h2pre);

    // ---- BN2 + encoder ----
    bnstats_k<<<dim3(2048), blk, 0, stream>>>(h2pre, g2, be2, p2);
    bnapply_k<<<dim3(8192), blk, 0, stream>>>(h2pre, p2, h2n);
    gemm_k<256, 256, 0, float><<<dim3(1024), blk, 0, stream>>>(
        h2n, Wenct, benc, nullptr, (float*)d_out);
}